// Round 1
// baseline (700.583 us; speedup 1.0000x reference)
//
#include <hip/hip_runtime.h>
#include <math.h>

// Problem constants: B=8, C=256, Ci=128, H=W=64, N=4096, M=1024
#define NB   8
#define NC   256
#define NCI  128
#define NSP  4096
#define NM   1024

// Workspace layout (in floats)
static const size_t SZ_PROJ  = (size_t)NB * NCI * NSP;        // 4,194,304
static const size_t OFF_THETA = 0;
static const size_t OFF_GF    = SZ_PROJ;                      // full-res g conv
static const size_t OFF_PF    = 2 * SZ_PROJ;                  // full-res phi conv
static const size_t OFF_GP    = 3 * SZ_PROJ;                  // pooled g [8][128][1024]
static const size_t OFF_PP    = OFF_GP + (size_t)NB * NCI * NM;
static const size_t OFF_Y     = OFF_PP + (size_t)NB * NCI * NM; // y [8][128][4096]
static const size_t OFF_WY    = OFF_GF;                       // wy reuses gf+pf region
static const size_t OFF_S1    = OFF_Y + SZ_PROJ;              // 256 floats
static const size_t OFF_S2    = OFF_S1 + 256;                 // 256 floats

__global__ void zero_stats(float* s) { s[threadIdx.x] = 0.f; }

// Generic 1x1-conv GEMM: out[b][o][n] = sum_c w[o][c]*in[b][c][n] + bias[o]
// Optional fused per-channel sum / sumsq accumulation (for BN stats).
__global__ __launch_bounds__(256) void conv_gemm(
    const float* __restrict__ in, const float* __restrict__ w,
    const float* __restrict__ bias, float* __restrict__ out,
    int O, int CIN, float* __restrict__ s1g, float* __restrict__ s2g)
{
  __shared__ float wt[32][68];   // [k][o], padded stride 68
  __shared__ float xs[32][64];   // [k][n]
  const int b  = blockIdx.z;
  const int o0 = blockIdx.y << 6;
  const int n0 = blockIdx.x << 6;
  const int tid = threadIdx.x;
  const int og = tid >> 4, ng = tid & 15;
  float acc[4][4] = {};
  const float* inb = in + (size_t)b * CIN * NSP;

  for (int k0 = 0; k0 < CIN; k0 += 32) {
    __syncthreads();
    // W tile (64 o x 32 k) -> wt[k][o] (transposed)
    {
      int q = tid;
#pragma unroll
      for (int it = 0; it < 2; ++it, q += 256) {
        int r = q >> 3, c4 = (q & 7) << 2;
        float4 v = *(const float4*)&w[(size_t)(o0 + r) * CIN + k0 + c4];
        wt[c4][r] = v.x; wt[c4 + 1][r] = v.y; wt[c4 + 2][r] = v.z; wt[c4 + 3][r] = v.w;
      }
    }
    // X tile (32 k x 64 n)
    {
      int q = tid;
#pragma unroll
      for (int it = 0; it < 2; ++it, q += 256) {
        int r = q >> 4, c4 = (q & 15) << 2;
        *(float4*)&xs[r][c4] = *(const float4*)&inb[(size_t)(k0 + r) * NSP + n0 + c4];
      }
    }
    __syncthreads();
#pragma unroll
    for (int kk = 0; kk < 32; ++kk) {
      float a[4], xv[4];
      *(float4*)a  = *(const float4*)&wt[kk][og << 2];
      *(float4*)xv = *(const float4*)&xs[kk][ng << 2];
#pragma unroll
      for (int i = 0; i < 4; ++i)
#pragma unroll
        for (int j = 0; j < 4; ++j)
          acc[i][j] += a[i] * xv[j];
    }
  }

  const int ob = o0 + (og << 2), nb = n0 + (ng << 2);
#pragma unroll
  for (int i = 0; i < 4; ++i) {
    float bi = bias[ob + i];
    float4 r;
    r.x = acc[i][0] + bi; r.y = acc[i][1] + bi;
    r.z = acc[i][2] + bi; r.w = acc[i][3] + bi;
    *(float4*)&out[((size_t)b * O + ob + i) * NSP + nb] = r;
    if (s1g != nullptr) {
      float s  = r.x + r.y + r.z + r.w;
      float sq = r.x * r.x + r.y * r.y + r.z * r.z + r.w * r.w;
#pragma unroll
      for (int d = 1; d < 16; d <<= 1) {
        s  += __shfl_xor(s, d);
        sq += __shfl_xor(sq, d);
      }
      if (ng == 0) { atomicAdd(&s1g[ob + i], s); atomicAdd(&s2g[ob + i], sq); }
    }
  }
}

// 2x2 maxpool for both g and phi full-res conv outputs.
__global__ __launch_bounds__(256) void pool_kernel(
    const float* __restrict__ gf, const float* __restrict__ pf,
    float* __restrict__ gp, float* __restrict__ pp)
{
  int idx = blockIdx.x * 256 + threadIdx.x;     // 0 .. 2*2^20-1
  const float* src = (idx >> 20) ? pf : gf;
  float*       dst = (idx >> 20) ? pp : gp;
  int r  = idx & 0xFFFFF;
  int bc = r >> 10, pos = r & 1023;
  int h2 = pos >> 5, w2 = pos & 31;
  const float* p = src + (size_t)bc * NSP + (h2 << 7) + (w2 << 1);
  float v = fmaxf(fmaxf(p[0], p[1]), fmaxf(p[64], p[65]));
  dst[(size_t)bc * NM + pos] = v;
}

// Flash attention: 32 queries per block, 16 key tiles of 64.
// theta [B][Ci][N], phi/g pooled [B][Ci][M], y out [B][Ci][N].
__global__ __launch_bounds__(256) void attn_kernel(
    const float* __restrict__ theta, const float* __restrict__ phi,
    const float* __restrict__ g, float* __restrict__ y)
{
  __shared__ float th[32][132];   // theta tile [q][k]
  __shared__ float kv[8320];      // phi: [128][64]; g: [64 m][130]
  __shared__ float ps[32][68];    // P tile [q][m]
  const int b  = blockIdx.y;
  const int n0 = blockIdx.x << 5;
  const int tid = threadIdx.x;
  const int qg = tid >> 4;        // 0..15: rows 2qg, 2qg+1
  const int cg = tid & 15;        // key-group / channel-group

  // theta tile: [128 c][32 n] -> th[n][c]
  {
    int q = tid;
#pragma unroll
    for (int it = 0; it < 4; ++it, q += 256) {
      int c = q >> 3, n4 = (q & 7) << 2;
      float4 v = *(const float4*)&theta[((size_t)b * NCI + c) * NSP + n0 + n4];
      th[n4][c] = v.x; th[n4 + 1][c] = v.y; th[n4 + 2][c] = v.z; th[n4 + 3][c] = v.w;
    }
  }

  float m_i[2] = {-3.0e38f, -3.0e38f};
  float l_i[2] = {0.f, 0.f};
  float ya[2][8] = {};

  for (int mt = 0; mt < 16; ++mt) {
    const int m0 = mt << 6;
    __syncthreads();  // theta visible (iter0) / prev PV done with kv,ps
    // phi tile -> kv[c*64+m]
    {
      int q = tid;
#pragma unroll
      for (int it = 0; it < 8; ++it, q += 256) {
        int c = q >> 4, m4 = (q & 15) << 2;
        *(float4*)&kv[c * 64 + m4] =
            *(const float4*)&phi[((size_t)b * NCI + c) * NM + m0 + m4];
      }
    }
    __syncthreads();

    // S = theta x phi : rows {2qg,2qg+1}, cols 4cg..4cg+3
    float s0[4] = {0, 0, 0, 0}, s1[4] = {0, 0, 0, 0};
    const float* thr0 = &th[0][0] + (2 * qg) * 132;
    const float* thr1 = thr0 + 132;
#pragma unroll 4
    for (int k = 0; k < 128; k += 4) {
      float a0[4], a1[4];
      *(float4*)a0 = *(const float4*)(thr0 + k);
      *(float4*)a1 = *(const float4*)(thr1 + k);
#pragma unroll
      for (int kk = 0; kk < 4; ++kk) {
        float p[4];
        *(float4*)p = *(const float4*)&kv[(k + kk) * 64 + (cg << 2)];
#pragma unroll
        for (int j = 0; j < 4; ++j) { s0[j] += a0[kk] * p[j]; s1[j] += a1[kk] * p[j]; }
      }
    }

    // online softmax update
    float pmax0 = fmaxf(fmaxf(s0[0], s0[1]), fmaxf(s0[2], s0[3]));
    float pmax1 = fmaxf(fmaxf(s1[0], s1[1]), fmaxf(s1[2], s1[3]));
#pragma unroll
    for (int d = 1; d < 16; d <<= 1) {
      pmax0 = fmaxf(pmax0, __shfl_xor(pmax0, d));
      pmax1 = fmaxf(pmax1, __shfl_xor(pmax1, d));
    }
    float mn0 = fmaxf(m_i[0], pmax0), mn1 = fmaxf(m_i[1], pmax1);
    float sc0 = __expf(m_i[0] - mn0), sc1 = __expf(m_i[1] - mn1);
    float p0e[4], p1e[4];
    float rs0 = 0.f, rs1 = 0.f;
#pragma unroll
    for (int j = 0; j < 4; ++j) {
      p0e[j] = __expf(s0[j] - mn0); rs0 += p0e[j];
      p1e[j] = __expf(s1[j] - mn1); rs1 += p1e[j];
    }
#pragma unroll
    for (int d = 1; d < 16; d <<= 1) {
      rs0 += __shfl_xor(rs0, d);
      rs1 += __shfl_xor(rs1, d);
    }
    l_i[0] = l_i[0] * sc0 + rs0; l_i[1] = l_i[1] * sc1 + rs1;
    m_i[0] = mn0; m_i[1] = mn1;
#pragma unroll
    for (int j = 0; j < 8; ++j) { ya[0][j] *= sc0; ya[1][j] *= sc1; }
    *(float4*)&ps[2 * qg][cg << 2]     = *(float4*)p0e;
    *(float4*)&ps[2 * qg + 1][cg << 2] = *(float4*)p1e;

    __syncthreads();  // ps written; done reading phi
    // g tile -> kv[m*130 + c] (transposed)
    {
      int q = tid;
#pragma unroll
      for (int it = 0; it < 8; ++it, q += 256) {
        int c = q >> 4, m4 = (q & 15) << 2;
        float4 v = *(const float4*)&g[((size_t)b * NCI + c) * NM + m0 + m4];
        kv[(m4)*130 + c]     = v.x;
        kv[(m4 + 1) * 130 + c] = v.y;
        kv[(m4 + 2) * 130 + c] = v.z;
        kv[(m4 + 3) * 130 + c] = v.w;
      }
    }
    __syncthreads();

    // PV: ya[i][j] += P[row i][m] * g[m][cg+16j]
    const float* pr0 = &ps[2 * qg][0];
    const float* pr1 = &ps[2 * qg + 1][0];
#pragma unroll 4
    for (int m = 0; m < 64; ++m) {
      float p0 = pr0[m], p1 = pr1[m];
      const float* gr = &kv[m * 130 + cg];
#pragma unroll
      for (int j = 0; j < 8; ++j) {
        float gv = gr[j << 4];
        ya[0][j] += p0 * gv;
        ya[1][j] += p1 * gv;
      }
    }
  }

  // finalize + coalesced write via LDS (reuse th)
  __syncthreads();
  float inv0 = 1.f / l_i[0], inv1 = 1.f / l_i[1];
  float* ys = &th[0][0];  // [32 q][132], use first 128 cols
#pragma unroll
  for (int j = 0; j < 8; ++j) {
    int c = cg + (j << 4);
    ys[(2 * qg) * 132 + c]     = ya[0][j] * inv0;
    ys[(2 * qg + 1) * 132 + c] = ya[1][j] * inv1;
  }
  __syncthreads();
  {
    int q = tid;
#pragma unroll
    for (int it = 0; it < 16; ++it, q += 256) {
      int c = q >> 5, qq = q & 31;
      y[((size_t)b * NCI + c) * NSP + n0 + qq] = ys[qq * 132 + c];
    }
  }
}

// BN (batch stats) + affine + residual
__global__ __launch_bounds__(256) void bn_res_kernel(
    const float* __restrict__ wy, const float* __restrict__ x,
    const float* __restrict__ s1, const float* __restrict__ s2,
    const float* __restrict__ gamma, const float* __restrict__ beta,
    float* __restrict__ out)
{
  int idx = blockIdx.x * 256 + threadIdx.x;
  int c = (idx >> 12) & 255;
  const float cnt = 1.f / 32768.f;   // B*H*W
  float mean = s1[c] * cnt;
  float var  = s2[c] * cnt - mean * mean;
  float inv  = rsqrtf(var + 1e-5f) * gamma[c];
  out[idx] = (wy[idx] - mean) * inv + beta[c] + x[idx];
}

extern "C" void kernel_launch(void* const* d_in, const int* in_sizes, int n_in,
                              void* d_out, int out_size, void* d_ws, size_t ws_size,
                              hipStream_t stream) {
  const float* x    = (const float*)d_in[0];
  const float* w_g  = (const float*)d_in[1];
  const float* b_g  = (const float*)d_in[2];
  const float* w_th = (const float*)d_in[3];
  const float* b_th = (const float*)d_in[4];
  const float* w_ph = (const float*)d_in[5];
  const float* b_ph = (const float*)d_in[6];
  const float* w_w  = (const float*)d_in[7];
  const float* b_w  = (const float*)d_in[8];
  const float* gam  = (const float*)d_in[9];
  const float* bet  = (const float*)d_in[10];
  float* out = (float*)d_out;
  float* ws  = (float*)d_ws;

  float* thbuf = ws + OFF_THETA;
  float* gf    = ws + OFF_GF;
  float* pf    = ws + OFF_PF;
  float* gp    = ws + OFF_GP;
  float* pp    = ws + OFF_PP;
  float* yb    = ws + OFF_Y;
  float* wy    = ws + OFF_WY;
  float* s1    = ws + OFF_S1;
  float* s2    = ws + OFF_S2;

  zero_stats<<<dim3(1), dim3(512), 0, stream>>>(s1);  // zeros s1 and s2 (contiguous)

  // projections (theta full-res; g/phi full-res then pooled)
  conv_gemm<<<dim3(64, 2, 8), 256, 0, stream>>>(x, w_th, b_th, thbuf, NCI, NC, nullptr, nullptr);
  conv_gemm<<<dim3(64, 2, 8), 256, 0, stream>>>(x, w_g,  b_g,  gf,    NCI, NC, nullptr, nullptr);
  conv_gemm<<<dim3(64, 2, 8), 256, 0, stream>>>(x, w_ph, b_ph, pf,    NCI, NC, nullptr, nullptr);

  pool_kernel<<<dim3(8192), 256, 0, stream>>>(gf, pf, gp, pp);

  attn_kernel<<<dim3(128, 8), 256, 0, stream>>>(thbuf, pp, gp, yb);

  // W conv + fused BN statistics
  conv_gemm<<<dim3(64, 4, 8), 256, 0, stream>>>(yb, w_w, b_w, wy, NC, NCI, s1, s2);

  bn_res_kernel<<<dim3(32768), 256, 0, stream>>>(wy, x, s1, s2, gam, bet, out);
}

// Round 2
// 237.525 us; speedup vs baseline: 2.9495x; 2.9495x over previous
//
#include <hip/hip_runtime.h>
#include <hip/hip_bf16.h>
#include <math.h>

// Problem constants: B=8, C=256, Ci=128, H=W=64, N=4096, M=1024
#define NB 8
#define NC 256
#define NCI 128
#define NSP 4096
#define NM 1024

typedef float f32x4 __attribute__((ext_vector_type(4)));
typedef short s16x8 __attribute__((ext_vector_type(8)));

// Workspace layout (byte offsets)
#define OFF_THT (0ull)          // theta^T bf16 [B][N][Ci]      8 MB
#define OFF_GF  (8ull << 20)    // g   full fp32 [B][Ci][N]    16 MB
#define OFF_PF  (24ull << 20)   // phi full fp32 [B][Ci][N]    16 MB
#define OFF_PHT (40ull << 20)   // phi^T pooled bf16 [B][M][Ci] 2 MB
#define OFF_GP  (42ull << 20)   // g pooled bf16 [B][Ci][M]     2 MB
#define OFF_YT  (44ull << 20)   // y^T fp32 [B][N][Ci]         16 MB
#define OFF_WY  (8ull << 20)    // wy fp32 [B][C][N] 32 MB (reuses GF+PF, dead by then)
#define OFF_S   (60ull << 20)   // stats: 512 floats

__device__ __forceinline__ unsigned short f2bf(float f) {
  union { __hip_bfloat16 h; unsigned short u; } v;
  v.h = __float2bfloat16(f);
  return v.u;
}

__global__ void zero_stats(float* s) { s[threadIdx.x] = 0.f; }

// ---------------- fp32 tiled GEMM: out[b][o][n] = sum_c w[o][c] in[b][c][n] + bias ----
__global__ __launch_bounds__(256) void conv_gemm(
    const float* __restrict__ in, const float* __restrict__ w,
    const float* __restrict__ bias, float* __restrict__ out,
    int O, int CIN)
{
  __shared__ float wt[32][68];
  __shared__ float xs[32][64];
  const int b = blockIdx.z, o0 = blockIdx.y << 6, n0 = blockIdx.x << 6;
  const int tid = threadIdx.x, og = tid >> 4, ng = tid & 15;
  float acc[4][4] = {};
  const float* inb = in + (size_t)b * CIN * NSP;

  for (int k0 = 0; k0 < CIN; k0 += 32) {
    __syncthreads();
    {
      int q = tid;
#pragma unroll
      for (int it = 0; it < 2; ++it, q += 256) {
        int r = q >> 3, c4 = (q & 7) << 2;
        float4 v = *(const float4*)&w[(size_t)(o0 + r) * CIN + k0 + c4];
        wt[c4][r] = v.x; wt[c4 + 1][r] = v.y; wt[c4 + 2][r] = v.z; wt[c4 + 3][r] = v.w;
      }
    }
    {
      int q = tid;
#pragma unroll
      for (int it = 0; it < 2; ++it, q += 256) {
        int r = q >> 4, c4 = (q & 15) << 2;
        *(float4*)&xs[r][c4] = *(const float4*)&inb[(size_t)(k0 + r) * NSP + n0 + c4];
      }
    }
    __syncthreads();
#pragma unroll
    for (int kk = 0; kk < 32; ++kk) {
      float a[4], xv[4];
      *(float4*)a = *(const float4*)&wt[kk][og << 2];
      *(float4*)xv = *(const float4*)&xs[kk][ng << 2];
#pragma unroll
      for (int i = 0; i < 4; ++i)
#pragma unroll
        for (int j = 0; j < 4; ++j) acc[i][j] += a[i] * xv[j];
    }
  }
  const int ob = o0 + (og << 2), nb = n0 + (ng << 2);
#pragma unroll
  for (int i = 0; i < 4; ++i) {
    float bi = bias[ob + i];
    float4 r;
    r.x = acc[i][0] + bi; r.y = acc[i][1] + bi;
    r.z = acc[i][2] + bi; r.w = acc[i][3] + bi;
    *(float4*)&out[((size_t)b * O + ob + i) * NSP + nb] = r;
  }
}

// ---------------- theta projection with transposed bf16 epilogue: thT[b][n][c] --------
__global__ __launch_bounds__(256) void conv_theta(
    const float* __restrict__ in, const float* __restrict__ w,
    const float* __restrict__ bias, unsigned short* __restrict__ outT)
{
  __shared__ float wt[32][68];
  __shared__ float xs[32][64];
  const int b = blockIdx.z, o0 = blockIdx.y << 6, n0 = blockIdx.x << 6;
  const int tid = threadIdx.x, og = tid >> 4, ng = tid & 15;
  float acc[4][4] = {};
  const float* inb = in + (size_t)b * NC * NSP;

  for (int k0 = 0; k0 < NC; k0 += 32) {
    __syncthreads();
    {
      int q = tid;
#pragma unroll
      for (int it = 0; it < 2; ++it, q += 256) {
        int r = q >> 3, c4 = (q & 7) << 2;
        float4 v = *(const float4*)&w[(size_t)(o0 + r) * NC + k0 + c4];
        wt[c4][r] = v.x; wt[c4 + 1][r] = v.y; wt[c4 + 2][r] = v.z; wt[c4 + 3][r] = v.w;
      }
    }
    {
      int q = tid;
#pragma unroll
      for (int it = 0; it < 2; ++it, q += 256) {
        int r = q >> 4, c4 = (q & 15) << 2;
        *(float4*)&xs[r][c4] = *(const float4*)&inb[(size_t)(k0 + r) * NSP + n0 + c4];
      }
    }
    __syncthreads();
#pragma unroll
    for (int kk = 0; kk < 32; ++kk) {
      float a[4], xv[4];
      *(float4*)a = *(const float4*)&wt[kk][og << 2];
      *(float4*)xv = *(const float4*)&xs[kk][ng << 2];
#pragma unroll
      for (int i = 0; i < 4; ++i)
#pragma unroll
        for (int j = 0; j < 4; ++j) acc[i][j] += a[i] * xv[j];
    }
  }
  const int ob = o0 + (og << 2), nb0 = n0 + (ng << 2);
  float bv[4];
#pragma unroll
  for (int i = 0; i < 4; ++i) bv[i] = bias[ob + i];
#pragma unroll
  for (int j = 0; j < 4; ++j) {
    ushort4 u;
    u.x = f2bf(acc[0][j] + bv[0]);
    u.y = f2bf(acc[1][j] + bv[1]);
    u.z = f2bf(acc[2][j] + bv[2]);
    u.w = f2bf(acc[3][j] + bv[3]);
    *(ushort4*)&outT[((size_t)b * NSP + nb0 + j) * NCI + ob] = u;
  }
}

// ---------------- 2x2 maxpool + layout transform to bf16 ----------------------------
// phi -> phT[b][m][c] (transposed), g -> gp[b][c][m] (kept c-major)
__global__ __launch_bounds__(256) void pool_kernel(
    const float* __restrict__ gf, const float* __restrict__ pf,
    unsigned short* __restrict__ gp, unsigned short* __restrict__ phT)
{
  __shared__ float raw[64][66];
  __shared__ float po[32][34];
  const int h2 = blockIdx.x, c0 = blockIdx.y << 5, z = blockIdx.z;
  const int is_phi = z >> 3, b = z & 7;
  const float* src = (is_phi ? pf : gf) + (size_t)b * NCI * NSP;
  const int t = threadIdx.x;
#pragma unroll
  for (int i = 0; i < 4; ++i) {
    int idx = i * 256 + t;
    int r = idx >> 4, w4 = (idx & 15) << 2;
    *(float4*)&raw[r][w4] =
        *(const float4*)&src[(size_t)(c0 + (r >> 1)) * NSP + (((h2 << 1) + (r & 1)) << 6) + w4];
  }
  __syncthreads();
#pragma unroll
  for (int p = 0; p < 4; ++p) {
    int o = p * 256 + t;
    int c = o >> 5, w2 = o & 31;
    po[c][w2] = fmaxf(fmaxf(raw[2 * c][2 * w2], raw[2 * c][2 * w2 + 1]),
                      fmaxf(raw[2 * c + 1][2 * w2], raw[2 * c + 1][2 * w2 + 1]));
  }
  __syncthreads();
  if (is_phi) {
    int w2 = t >> 3, c4 = (t & 7) << 2;
    ushort4 u;
    u.x = f2bf(po[c4][w2]);     u.y = f2bf(po[c4 + 1][w2]);
    u.z = f2bf(po[c4 + 2][w2]); u.w = f2bf(po[c4 + 3][w2]);
    *(ushort4*)&phT[((size_t)b * NM + (h2 << 5) + w2) * NCI + c0 + c4] = u;
  } else {
    int c = t >> 3, m4 = (t & 7) << 2;
    ushort4 u;
    u.x = f2bf(po[c][m4]);     u.y = f2bf(po[c][m4 + 1]);
    u.z = f2bf(po[c][m4 + 2]); u.w = f2bf(po[c][m4 + 3]);
    *(ushort4*)&gp[((size_t)b * NCI + c0 + c) * NM + (h2 << 5) + m4] = u;
  }
}

// ---------------- MFMA flash attention ----------------------------------------------
// thT [B][N][Ci] bf16, phT [B][M][Ci] bf16, gp [B][Ci][M] bf16 -> yT [B][N][Ci] f32
__global__ __launch_bounds__(512, 1) void attn_mfma(
    const unsigned short* __restrict__ thT, const unsigned short* __restrict__ phT,
    const unsigned short* __restrict__ gP, float* __restrict__ yT)
{
  __shared__ unsigned short phs[64 * 128];   // phi^T tile [m][c]  (swizzled)
  __shared__ unsigned short gs[128 * 64];    // g tile [c][m]      (swizzled)
  __shared__ unsigned short ps[8][16 * 72];  // per-wave P [q][m]  (stride 72)

  const int b = blockIdx.y;
  const int n0 = blockIdx.x << 7;
  const int tid = threadIdx.x;
  const int wave = tid >> 6;
  const int lane = tid & 63;
  const int lo16 = lane & 15;
  const int hi4 = lane >> 4;
  const int qbase = n0 + (wave << 4);
  const int swq = (lo16 & 7) << 4;

  // theta A-fragments, kept in registers for the whole kernel
  s16x8 tha[4];
#pragma unroll
  for (int kc = 0; kc < 4; ++kc)
    tha[kc] = *(const s16x8*)&thT[((size_t)b * NSP + qbase + lo16) * NCI + kc * 32 + hi4 * 8];

  f32x4 yacc[8];
#pragma unroll
  for (int i = 0; i < 8; ++i) yacc[i] = (f32x4){0.f, 0.f, 0.f, 0.f};
  float m_i[4] = {-3e38f, -3e38f, -3e38f, -3e38f};
  float l_i[4] = {0.f, 0.f, 0.f, 0.f};

  for (int mt = 0; mt < 16; ++mt) {
    const int m0 = mt << 6;
    __syncthreads();   // everyone done reading LDS tiles of previous iter
    // stage phi^T tile [64 m][128 c]: linear LDS dest, XOR-swizzled global source
#pragma unroll
    for (int i = 0; i < 2; ++i) {
      int ofs = (i * 512 + tid) * 16;
      int m = ofs >> 8, cb = ofs & 255;
      const char* src = (const char*)phT + (((size_t)b * NM + m0 + m) << 8) + (cb ^ ((m & 7) << 4));
      char* dst = (char*)phs + (size_t)(i * 512 + (tid & ~63)) * 16;
      __builtin_amdgcn_global_load_lds((const __attribute__((address_space(1))) unsigned*)src,
                                       (__attribute__((address_space(3))) unsigned*)dst, 16, 0, 0);
    }
    // stage g tile [128 c][64 m]
#pragma unroll
    for (int i = 0; i < 2; ++i) {
      int ofs = (i * 512 + tid) * 16;
      int c = ofs >> 7, mb = ofs & 127;
      const char* src = (const char*)gP + (((size_t)b * NCI + c) << 11) + m0 * 2 + (mb ^ ((c & 7) << 4));
      char* dst = (char*)gs + (size_t)(i * 512 + (tid & ~63)) * 16;
      __builtin_amdgcn_global_load_lds((const __attribute__((address_space(1))) unsigned*)src,
                                       (__attribute__((address_space(3))) unsigned*)dst, 16, 0, 0);
    }
    __syncthreads();   // tiles landed (compiler drains vmcnt before barrier)

    // S = theta x phi^T : D[q][m], rows q=hi4*4+r, cols m=ms*16+lo16
    f32x4 sf[4];
#pragma unroll
    for (int ms = 0; ms < 4; ++ms) sf[ms] = (f32x4){0.f, 0.f, 0.f, 0.f};
#pragma unroll
    for (int ms = 0; ms < 4; ++ms) {
      const int rbase = (ms * 16 + lo16) << 8;
#pragma unroll
      for (int kc = 0; kc < 4; ++kc) {
        s16x8 bp = *(const s16x8*)((const char*)phs + rbase + ((kc * 64 + hi4 * 16) ^ swq));
        sf[ms] = __builtin_amdgcn_mfma_f32_16x16x32_bf16(tha[kc], bp, sf[ms], 0, 0, 0);
      }
    }

    // online softmax over m (4 in-thread cols x 16 lanes)
    float scv[4];
#pragma unroll
    for (int r = 0; r < 4; ++r) {
      float v = fmaxf(fmaxf(sf[0][r], sf[1][r]), fmaxf(sf[2][r], sf[3][r]));
      v = fmaxf(v, __shfl_xor(v, 1));
      v = fmaxf(v, __shfl_xor(v, 2));
      v = fmaxf(v, __shfl_xor(v, 4));
      v = fmaxf(v, __shfl_xor(v, 8));
      float mn = fmaxf(m_i[r], v);
      float sc = __expf(m_i[r] - mn);
      float rs = 0.f;
#pragma unroll
      for (int ms = 0; ms < 4; ++ms) {
        float e = __expf(sf[ms][r] - mn);
        sf[ms][r] = e;
        rs += e;
      }
      rs += __shfl_xor(rs, 1);
      rs += __shfl_xor(rs, 2);
      rs += __shfl_xor(rs, 4);
      rs += __shfl_xor(rs, 8);
      l_i[r] = l_i[r] * sc + rs;
      m_i[r] = mn;
      scv[r] = sc;
    }
#pragma unroll
    for (int ct = 0; ct < 8; ++ct)
#pragma unroll
      for (int r = 0; r < 4; ++r) yacc[ct][r] *= scv[r];

    // P (bf16) -> per-wave LDS [16 q][stride 72], then read back as A-fragments
    unsigned short* pw = ps[wave];
#pragma unroll
    for (int ms = 0; ms < 4; ++ms)
#pragma unroll
      for (int r = 0; r < 4; ++r)
        pw[(hi4 * 4 + r) * 72 + ms * 16 + lo16] = f2bf(sf[ms][r]);
    asm volatile("s_waitcnt lgkmcnt(0)" ::: "memory");

    s16x8 pa[2];
#pragma unroll
    for (int km = 0; km < 2; ++km)
      pa[km] = *(const s16x8*)((const char*)pw + lo16 * 144 + km * 64 + hi4 * 16);

    // PV: y[q][c] += P[q][m] g[m][c]
#pragma unroll
    for (int ct = 0; ct < 8; ++ct) {
      const int rb = (ct * 16 + lo16) << 7;
#pragma unroll
      for (int km = 0; km < 2; ++km) {
        s16x8 bg = *(const s16x8*)((const char*)gs + rb + ((km * 64 + hi4 * 16) ^ swq));
        yacc[ct] = __builtin_amdgcn_mfma_f32_16x16x32_bf16(pa[km], bg, yacc[ct], 0, 0, 0);
      }
    }
  }

  // epilogue: y^T[b][n][c] = y / l
#pragma unroll
  for (int r = 0; r < 4; ++r) {
    float inv = 1.f / l_i[r];
    size_t row = ((size_t)b * NSP + qbase + hi4 * 4 + r) * NCI;
#pragma unroll
    for (int ct = 0; ct < 8; ++ct) yT[row + ct * 16 + lo16] = yacc[ct][r] * inv;
  }
}

// ---------------- W conv (input y^T [b][n][c] f32) + fused BN stats ------------------
__global__ __launch_bounds__(256) void conv_w(
    const float* __restrict__ yT, const float* __restrict__ w,
    const float* __restrict__ bias, float* __restrict__ out,
    float* __restrict__ s1g, float* __restrict__ s2g)
{
  __shared__ float wt[32][68];
  __shared__ float xs[32][68];
  const int b = blockIdx.z, o0 = blockIdx.y << 6, n0 = blockIdx.x << 6;
  const int tid = threadIdx.x, og = tid >> 4, ng = tid & 15;
  float acc[4][4] = {};

  for (int k0 = 0; k0 < NCI; k0 += 32) {
    __syncthreads();
    {
      int q = tid;
#pragma unroll
      for (int it = 0; it < 2; ++it, q += 256) {
        int r = q >> 3, c4 = (q & 7) << 2;
        float4 v = *(const float4*)&w[(size_t)(o0 + r) * NCI + k0 + c4];
        wt[c4][r] = v.x; wt[c4 + 1][r] = v.y; wt[c4 + 2][r] = v.z; wt[c4 + 3][r] = v.w;
      }
    }
    {
      int q = tid;
#pragma unroll
      for (int it = 0; it < 2; ++it, q += 256) {
        int n = q >> 3, c4 = (q & 7) << 2;
        float4 v = *(const float4*)&yT[((size_t)b * NSP + n0 + n) * NCI + k0 + c4];
        xs[c4][n] = v.x; xs[c4 + 1][n] = v.y; xs[c4 + 2][n] = v.z; xs[c4 + 3][n] = v.w;
      }
    }
    __syncthreads();
#pragma unroll
    for (int kk = 0; kk < 32; ++kk) {
      float a[4], xv[4];
      *(float4*)a = *(const float4*)&wt[kk][og << 2];
      *(float4*)xv = *(const float4*)&xs[kk][ng << 2];
#pragma unroll
      for (int i = 0; i < 4; ++i)
#pragma unroll
        for (int j = 0; j < 4; ++j) acc[i][j] += a[i] * xv[j];
    }
  }
  const int ob = o0 + (og << 2), nb = n0 + (ng << 2);
#pragma unroll
  for (int i = 0; i < 4; ++i) {
    float bi = bias[ob + i];
    float4 r;
    r.x = acc[i][0] + bi; r.y = acc[i][1] + bi;
    r.z = acc[i][2] + bi; r.w = acc[i][3] + bi;
    *(float4*)&out[((size_t)b * NC + ob + i) * NSP + nb] = r;
    float s = r.x + r.y + r.z + r.w;
    float sq = r.x * r.x + r.y * r.y + r.z * r.z + r.w * r.w;
#pragma unroll
    for (int d = 1; d < 16; d <<= 1) {
      s += __shfl_xor(s, d);
      sq += __shfl_xor(sq, d);
    }
    if (ng == 0) { atomicAdd(&s1g[ob + i], s); atomicAdd(&s2g[ob + i], sq); }
  }
}

// ---------------- BN (batch stats) + affine + residual -------------------------------
__global__ __launch_bounds__(256) void bn_res_kernel(
    const float* __restrict__ wy, const float* __restrict__ x,
    const float* __restrict__ s1, const float* __restrict__ s2,
    const float* __restrict__ gamma, const float* __restrict__ beta,
    float* __restrict__ out)
{
  int idx = blockIdx.x * 256 + threadIdx.x;
  int c = (idx >> 12) & 255;
  const float cnt = 1.f / 32768.f;
  float mean = s1[c] * cnt;
  float var = s2[c] * cnt - mean * mean;
  float inv = rsqrtf(var + 1e-5f) * gamma[c];
  out[idx] = (wy[idx] - mean) * inv + beta[c] + x[idx];
}

extern "C" void kernel_launch(void* const* d_in, const int* in_sizes, int n_in,
                              void* d_out, int out_size, void* d_ws, size_t ws_size,
                              hipStream_t stream) {
  const float* x    = (const float*)d_in[0];
  const float* w_g  = (const float*)d_in[1];
  const float* b_g  = (const float*)d_in[2];
  const float* w_th = (const float*)d_in[3];
  const float* b_th = (const float*)d_in[4];
  const float* w_ph = (const float*)d_in[5];
  const float* b_ph = (const float*)d_in[6];
  const float* w_w  = (const float*)d_in[7];
  const float* b_w  = (const float*)d_in[8];
  const float* gam  = (const float*)d_in[9];
  const float* bet  = (const float*)d_in[10];
  float* out = (float*)d_out;
  char* ws = (char*)d_ws;

  unsigned short* thT = (unsigned short*)(ws + OFF_THT);
  float*          gf  = (float*)(ws + OFF_GF);
  float*          pf  = (float*)(ws + OFF_PF);
  unsigned short* phT = (unsigned short*)(ws + OFF_PHT);
  unsigned short* gp  = (unsigned short*)(ws + OFF_GP);
  float*          yTb = (float*)(ws + OFF_YT);
  float*          wy  = (float*)(ws + OFF_WY);
  float*          s1  = (float*)(ws + OFF_S);
  float*          s2  = s1 + 256;

  zero_stats<<<dim3(1), dim3(512), 0, stream>>>(s1);

  conv_theta<<<dim3(64, 2, 8), 256, 0, stream>>>(x, w_th, b_th, thT);
  conv_gemm<<<dim3(64, 2, 8), 256, 0, stream>>>(x, w_g, b_g, gf, NCI, NC);
  conv_gemm<<<dim3(64, 2, 8), 256, 0, stream>>>(x, w_ph, b_ph, pf, NCI, NC);

  pool_kernel<<<dim3(32, 4, 16), 256, 0, stream>>>(gf, pf, gp, phT);

  attn_mfma<<<dim3(32, 8), 512, 0, stream>>>(thT, phT, gp, yTb);

  conv_w<<<dim3(64, 4, 8), 256, 0, stream>>>(yTb, w_w, b_w, wy, s1, s2);

  bn_res_kernel<<<dim3(32768), 256, 0, stream>>>(wy, x, s1, s2, gam, bet, out);
}

// Round 4
// 129.903 us; speedup vs baseline: 5.3931x; 1.8285x over previous
//
#include <hip/hip_runtime.h>
#include <hip/hip_bf16.h>

// Problem constants: B=8, C=256, Ci=128, H=W=64, N=4096, M=1024
#define NB 8
#define NC 256
#define NCI 128
#define NSP 4096
#define NM 1024

typedef float f32x4 __attribute__((ext_vector_type(4)));
typedef short s16x8 __attribute__((ext_vector_type(8)));
typedef unsigned short u16;

// Workspace layout (byte offsets, total < 64 MB)
#define OFF_XH  (0ull)              // xh bf16 [B][N][C]  16 MB (dead after proj)
#define OFF_XL  (16777216ull)       // xl bf16 [B][N][C]  16 MB (dead after proj)
#define OFF_THT (33554432ull)       // thT bf16 [B][N][Ci] 8 MB (dead after attn)
#define OFF_PHT (41943040ull)       // phT bf16 [B][M][Ci] 2 MB
#define OFF_GP  (44040192ull)       // gp  bf16 [B][Ci][M] 2 MB
#define OFF_YH  (46137344ull)       // yh  bf16 [B][N][Ci] 8 MB
#define OFF_YL  (54525952ull)       // yl  bf16 [B][N][Ci] 8 MB
#define OFF_WY  (0ull)              // wy f32 [B][C][N] 32 MB (overlays XH+XL, dead)
#define OFF_WBH (62914560ull)       // wb hi bf16 [384][256] 192 KB
#define OFF_WBL (63111168ull)       // wb lo
#define OFF_WWH (63307776ull)       // wwb hi bf16 [256][128] 64 KB
#define OFF_WWL (63373312ull)       // wwb lo
#define OFF_S   (63438848ull)       // s1[256], s2[256] f32

__device__ __forceinline__ u16 f2bf(float f) {
  union { __hip_bfloat16 h; u16 u; } v;
  v.h = __float2bfloat16(f);
  return v.u;
}
__device__ __forceinline__ float bf2f(u16 u) {
  union { unsigned u; float f; } v;
  v.u = (unsigned)u << 16;
  return v.f;
}
__device__ __forceinline__ u16 bfmax4(u16 a, u16 b, u16 c, u16 d) {
  float v = fmaxf(fmaxf(bf2f(a), bf2f(b)), fmaxf(bf2f(c), bf2f(d)));
  return f2bf(v);
}

__global__ void zero_stats(float* s) { s[threadIdx.x] = 0.f; }

// ---- weights -> bf16 hi/lo (wb stacked: rows 0-127 g, 128-255 theta, 256-383 phi) --
__global__ __launch_bounds__(256) void wcvt(
    const float* __restrict__ wg, const float* __restrict__ wth,
    const float* __restrict__ wph, const float* __restrict__ ww,
    u16* __restrict__ wbh, u16* __restrict__ wbl,
    u16* __restrict__ wwh, u16* __restrict__ wwl)
{
  int idx = blockIdx.x * 256 + threadIdx.x;
  if (idx < 384 * 256) {
    int row = idx >> 8, k = idx & 255;
    float v = row < 128 ? wg[row * 256 + k]
            : row < 256 ? wth[(row - 128) * 256 + k]
                        : wph[(row - 256) * 256 + k];
    u16 h = f2bf(v);
    wbh[idx] = h;
    wbl[idx] = f2bf(v - bf2f(h));
  } else {
    int j = idx - 384 * 256;
    float v = ww[j];
    u16 h = f2bf(v);
    wwh[j] = h;
    wwl[j] = f2bf(v - bf2f(h));
  }
}

// ---- x [B][C][N] f32 -> xh/xl [B][N][C] bf16 hi/lo (transpose + split) -------------
__global__ __launch_bounds__(256) void xt_cvt(const float* __restrict__ x,
                                              u16* __restrict__ xh, u16* __restrict__ xl)
{
  __shared__ float t[64 * 68];
  const int n0 = blockIdx.x << 6, c0 = blockIdx.y << 6, b = blockIdx.z;
  const int tid = threadIdx.x;
  const int cl = tid >> 4, n4 = (tid & 15) << 2;
#pragma unroll
  for (int it = 0; it < 4; ++it) {
    int c = it * 16 + cl;
    float4 v = *(const float4*)&x[((size_t)(b * NC + c0 + c)) * NSP + n0 + n4];
    *(float4*)&t[c * 68 + n4] = v;
  }
  __syncthreads();
#pragma unroll
  for (int it = 0; it < 2; ++it) {
    int task = it * 256 + tid;
    int n = task >> 3, cc = (task & 7) << 3;
    u16 oh[8], ol[8];
#pragma unroll
    for (int i = 0; i < 8; ++i) {
      float v = t[(cc + i) * 68 + n];
      oh[i] = f2bf(v);
      ol[i] = f2bf(v - bf2f(oh[i]));
    }
    size_t dst = ((size_t)(b * NSP + n0 + n)) * NC + c0 + cc;
    *(s16x8*)&xh[dst] = *(s16x8*)oh;
    *(s16x8*)&xl[dst] = *(s16x8*)ol;
  }
}

// ---- fused projection: all 384 channels, 3-pass split MFMA, bias+pool+layouts ------
// Block: (h2, b). Output tile O=384 x N=128 (spatial rows 2h2, 2h2+1). K in 4 steps of 64.
__global__ __launch_bounds__(512, 1) void proj_fused(
    const u16* __restrict__ xh, const u16* __restrict__ xl,
    const u16* __restrict__ wbh, const u16* __restrict__ wbl,
    const float* __restrict__ bg, const float* __restrict__ bth,
    const float* __restrict__ bph,
    u16* __restrict__ thT, u16* __restrict__ phT, u16* __restrict__ gp)
{
  __shared__ char smem[132608];
  u16* xsh = (u16*)smem;                 // [128 n][64 k]  16 KB swizzled
  u16* xsl = (u16*)(smem + 16384);       // [128 n][64 k]  16 KB
  u16* wsh = (u16*)(smem + 32768);       // [384 o][64 k]  48 KB
  u16* wsl = (u16*)(smem + 81920);       // [384 o][64 k]  48 KB
  u16* outl = (u16*)smem;                // epilogue [384][137] bf16 (105216 B, overlays)
  float* bias = (float*)(smem + 131072); // 384 f32

  const int b = blockIdx.y, h2 = blockIdx.x;
  const int n0 = h2 << 7;
  const int tid = threadIdx.x;
  const int wave = tid >> 6, lane = tid & 63;
  const int lo16 = lane & 15, hi4 = lane >> 4;
  const int wr = wave >> 1, wc = wave & 1;
  const int obase = wr * 96, nbase = wc * 64;

  if (tid < 384)
    bias[tid] = tid < 128 ? bg[tid] : tid < 256 ? bth[tid - 128] : bph[tid - 256];

  f32x4 acc[6][4];
#pragma unroll
  for (int i = 0; i < 6; ++i)
#pragma unroll
    for (int j = 0; j < 4; ++j) acc[i][j] = (f32x4){0.f, 0.f, 0.f, 0.f};

  for (int step = 0; step < 4; ++step) {
    __syncthreads();  // previous MFMA done with tiles
    // stage x hi/lo tiles [128][64] (1024 chunks each)
#pragma unroll
    for (int i = 0; i < 2; ++i) {
      int ci = i * 512 + tid;
      int n = ci >> 3, slot = ci & 7;
      size_t rowb = ((size_t)(b * NSP + n0 + n)) * 512 + step * 128 + ((slot ^ (n & 7)) << 4);
      char* dsth = (char*)xsh + (size_t)(i * 512 + (tid & ~63)) * 16;
      char* dstl = (char*)xsl + (size_t)(i * 512 + (tid & ~63)) * 16;
      __builtin_amdgcn_global_load_lds((const __attribute__((address_space(1))) unsigned*)((const char*)xh + rowb),
                                       (__attribute__((address_space(3))) unsigned*)dsth, 16, 0, 0);
      __builtin_amdgcn_global_load_lds((const __attribute__((address_space(1))) unsigned*)((const char*)xl + rowb),
                                       (__attribute__((address_space(3))) unsigned*)dstl, 16, 0, 0);
    }
    // stage weight hi/lo tiles [384][64] (3072 chunks each)
#pragma unroll
    for (int i = 0; i < 6; ++i) {
      int ci = i * 512 + tid;
      int o = ci >> 3, slot = ci & 7;
      size_t rowb = (size_t)o * 512 + step * 128 + ((slot ^ (o & 7)) << 4);
      char* dsth = (char*)wsh + (size_t)(i * 512 + (tid & ~63)) * 16;
      char* dstl = (char*)wsl + (size_t)(i * 512 + (tid & ~63)) * 16;
      __builtin_amdgcn_global_load_lds((const __attribute__((address_space(1))) unsigned*)((const char*)wbh + rowb),
                                       (__attribute__((address_space(3))) unsigned*)dsth, 16, 0, 0);
      __builtin_amdgcn_global_load_lds((const __attribute__((address_space(1))) unsigned*)((const char*)wbl + rowb),
                                       (__attribute__((address_space(3))) unsigned*)dstl, 16, 0, 0);
    }
    __syncthreads();  // tiles landed

#pragma unroll
    for (int kc = 0; kc < 2; ++kc) {
      const int sl = kc * 4 + hi4;
      s16x8 bfh[4], bfl[4];
#pragma unroll
      for (int fn = 0; fn < 4; ++fn) {
        int n = nbase + fn * 16 + lo16;
        int off = (int)n * 128 + ((sl ^ (n & 7)) << 4);
        bfh[fn] = *(const s16x8*)((const char*)xsh + off);
        bfl[fn] = *(const s16x8*)((const char*)xsl + off);
      }
#pragma unroll
      for (int fo = 0; fo < 6; ++fo) {
        int o = obase + fo * 16 + lo16;
        int off = (int)o * 128 + ((sl ^ (o & 7)) << 4);
        s16x8 afh = *(const s16x8*)((const char*)wsh + off);
        s16x8 afl = *(const s16x8*)((const char*)wsl + off);
#pragma unroll
        for (int fn = 0; fn < 4; ++fn) {
          acc[fo][fn] = __builtin_amdgcn_mfma_f32_16x16x32_bf16(afh, bfh[fn], acc[fo][fn], 0, 0, 0);
          acc[fo][fn] = __builtin_amdgcn_mfma_f32_16x16x32_bf16(afh, bfl[fn], acc[fo][fn], 0, 0, 0);
          acc[fo][fn] = __builtin_amdgcn_mfma_f32_16x16x32_bf16(afl, bfh[fn], acc[fo][fn], 0, 0, 0);
        }
      }
    }
  }

  __syncthreads();  // all MFMA done; staging buffers dead; outl overlays them
#pragma unroll
  for (int fo = 0; fo < 6; ++fo) {
    int orow = obase + fo * 16 + hi4 * 4;
    f32x4 bv = *(const f32x4*)&bias[orow];
#pragma unroll
    for (int fn = 0; fn < 4; ++fn) {
      int n = nbase + fn * 16 + lo16;
#pragma unroll
      for (int r = 0; r < 4; ++r)
        outl[(orow + r) * 137 + n] = f2bf(acc[fo][fn][r] + bv[r]);
    }
  }
  __syncthreads();

  // theta rows 128..255 -> thT[b][n][c]
#pragma unroll
  for (int it = 0; it < 4; ++it) {
    int task = it * 512 + tid;
    int n = task >> 4, cc = (task & 15) << 3;
    u16 o[8];
#pragma unroll
    for (int i = 0; i < 8; ++i) o[i] = outl[(128 + cc + i) * 137 + n];
    *(s16x8*)&thT[((size_t)(b * NSP + n0 + n)) * NCI + cc] = *(s16x8*)o;
  }
  // g rows 0..127, pooled -> gp[b][c][m]
  {
    int c = tid >> 2, wq = tid & 3;
    u16 o[8];
#pragma unroll
    for (int j = 0; j < 8; ++j) {
      int w2 = wq * 8 + j;
      o[j] = bfmax4(outl[c * 137 + 2 * w2], outl[c * 137 + 2 * w2 + 1],
                    outl[c * 137 + 64 + 2 * w2], outl[c * 137 + 64 + 2 * w2 + 1]);
    }
    *(s16x8*)&gp[((size_t)(b * NCI + c)) * NM + (h2 << 5) + wq * 8] = *(s16x8*)o;
  }
  // phi rows 256..383, pooled + transposed -> phT[b][m][c]
  {
    int w2 = tid >> 4, cc = (tid & 15) << 3;
    u16 o[8];
#pragma unroll
    for (int i = 0; i < 8; ++i) {
      int c = 256 + cc + i;
      o[i] = bfmax4(outl[c * 137 + 2 * w2], outl[c * 137 + 2 * w2 + 1],
                    outl[c * 137 + 64 + 2 * w2], outl[c * 137 + 64 + 2 * w2 + 1]);
    }
    *(s16x8*)&phT[((size_t)(b * NM + (h2 << 5) + w2)) * NCI + cc] = *(s16x8*)o;
  }
}

// ---- MFMA flash attention (round-2 validated); epilogue emits y hi/lo bf16 ---------
__global__ __launch_bounds__(512, 1) void attn_mfma(
    const u16* __restrict__ thT, const u16* __restrict__ phT,
    const u16* __restrict__ gP, u16* __restrict__ yh, u16* __restrict__ yl)
{
  __shared__ u16 phs[64 * 128];
  __shared__ u16 gs[128 * 64];
  __shared__ u16 ps[8][16 * 72];

  const int b = blockIdx.y;
  const int n0 = blockIdx.x << 7;
  const int tid = threadIdx.x;
  const int wave = tid >> 6;
  const int lane = tid & 63;
  const int lo16 = lane & 15;
  const int hi4 = lane >> 4;
  const int qbase = n0 + (wave << 4);
  const int swq = (lo16 & 7) << 4;

  s16x8 tha[4];
#pragma unroll
  for (int kc = 0; kc < 4; ++kc)
    tha[kc] = *(const s16x8*)&thT[((size_t)b * NSP + qbase + lo16) * NCI + kc * 32 + hi4 * 8];

  f32x4 yacc[8];
#pragma unroll
  for (int i = 0; i < 8; ++i) yacc[i] = (f32x4){0.f, 0.f, 0.f, 0.f};
  float m_i[4] = {-3e38f, -3e38f, -3e38f, -3e38f};
  float l_i[4] = {0.f, 0.f, 0.f, 0.f};

  for (int mt = 0; mt < 16; ++mt) {
    const int m0 = mt << 6;
    __syncthreads();
#pragma unroll
    for (int i = 0; i < 2; ++i) {
      int ofs = (i * 512 + tid) * 16;
      int m = ofs >> 8, cb = ofs & 255;
      const char* src = (const char*)phT + (((size_t)b * NM + m0 + m) << 8) + (cb ^ ((m & 7) << 4));
      char* dst = (char*)phs + (size_t)(i * 512 + (tid & ~63)) * 16;
      __builtin_amdgcn_global_load_lds((const __attribute__((address_space(1))) unsigned*)src,
                                       (__attribute__((address_space(3))) unsigned*)dst, 16, 0, 0);
    }
#pragma unroll
    for (int i = 0; i < 2; ++i) {
      int ofs = (i * 512 + tid) * 16;
      int c = ofs >> 7, mb = ofs & 127;
      const char* src = (const char*)gP + (((size_t)b * NCI + c) << 11) + m0 * 2 + (mb ^ ((c & 7) << 4));
      char* dst = (char*)gs + (size_t)(i * 512 + (tid & ~63)) * 16;
      __builtin_amdgcn_global_load_lds((const __attribute__((address_space(1))) unsigned*)src,
                                       (__attribute__((address_space(3))) unsigned*)dst, 16, 0, 0);
    }
    __syncthreads();

    f32x4 sf[4];
#pragma unroll
    for (int ms = 0; ms < 4; ++ms) sf[ms] = (f32x4){0.f, 0.f, 0.f, 0.f};
#pragma unroll
    for (int ms = 0; ms < 4; ++ms) {
      const int rbase = (ms * 16 + lo16) << 8;
#pragma unroll
      for (int kc = 0; kc < 4; ++kc) {
        s16x8 bp = *(const s16x8*)((const char*)phs + rbase + ((kc * 64 + hi4 * 16) ^ swq));
        sf[ms] = __builtin_amdgcn_mfma_f32_16x16x32_bf16(tha[kc], bp, sf[ms], 0, 0, 0);
      }
    }

    float scv[4];
#pragma unroll
    for (int r = 0; r < 4; ++r) {
      float v = fmaxf(fmaxf(sf[0][r], sf[1][r]), fmaxf(sf[2][r], sf[3][r]));
      v = fmaxf(v, __shfl_xor(v, 1));
      v = fmaxf(v, __shfl_xor(v, 2));
      v = fmaxf(v, __shfl_xor(v, 4));
      v = fmaxf(v, __shfl_xor(v, 8));
      float mn = fmaxf(m_i[r], v);
      float sc = __expf(m_i[r] - mn);
      float rs = 0.f;
#pragma unroll
      for (int ms = 0; ms < 4; ++ms) {
        float e = __expf(sf[ms][r] - mn);
        sf[ms][r] = e;
        rs += e;
      }
      rs += __shfl_xor(rs, 1);
      rs += __shfl_xor(rs, 2);
      rs += __shfl_xor(rs, 4);
      rs += __shfl_xor(rs, 8);
      l_i[r] = l_i[r] * sc + rs;
      m_i[r] = mn;
      scv[r] = sc;
    }
#pragma unroll
    for (int ct = 0; ct < 8; ++ct)
#pragma unroll
      for (int r = 0; r < 4; ++r) yacc[ct][r] *= scv[r];

    u16* pw = ps[wave];
#pragma unroll
    for (int ms = 0; ms < 4; ++ms)
#pragma unroll
      for (int r = 0; r < 4; ++r)
        pw[(hi4 * 4 + r) * 72 + ms * 16 + lo16] = f2bf(sf[ms][r]);
    asm volatile("s_waitcnt lgkmcnt(0)" ::: "memory");

    s16x8 pa[2];
#pragma unroll
    for (int km = 0; km < 2; ++km)
      pa[km] = *(const s16x8*)((const char*)pw + lo16 * 144 + km * 64 + hi4 * 16);

#pragma unroll
    for (int ct = 0; ct < 8; ++ct) {
      const int rb = (ct * 16 + lo16) << 7;
#pragma unroll
      for (int km = 0; km < 2; ++km) {
        s16x8 bg = *(const s16x8*)((const char*)gs + rb + ((km * 64 + hi4 * 16) ^ swq));
        yacc[ct] = __builtin_amdgcn_mfma_f32_16x16x32_bf16(pa[km], bg, yacc[ct], 0, 0, 0);
      }
    }
  }

#pragma unroll
  for (int r = 0; r < 4; ++r) {
    float inv = 1.f / l_i[r];
    size_t row = ((size_t)b * NSP + qbase + hi4 * 4 + r) * NCI;
#pragma unroll
    for (int ct = 0; ct < 8; ++ct) {
      float v = yacc[ct][r] * inv;
      u16 h = f2bf(v);
      yh[row + ct * 16 + lo16] = h;
      yl[row + ct * 16 + lo16] = f2bf(v - bf2f(h));
    }
  }
}

// ---- W conv 3-pass split MFMA + fused BN stats --------------------------------------
__global__ __launch_bounds__(512, 1) void conv_w_mfma(
    const u16* __restrict__ yh, const u16* __restrict__ yl,
    const u16* __restrict__ wwh, const u16* __restrict__ wwl,
    const float* __restrict__ bw, float* __restrict__ wy,
    float* __restrict__ s1g, float* __restrict__ s2g)
{
  __shared__ char smem[102400];
  u16* wsh = (u16*)smem;                  // [256 o][64 k] 32 KB swizzled
  u16* wsl = (u16*)(smem + 32768);
  u16* ysh = (u16*)(smem + 65536);        // [128 n][64 k] 16 KB
  u16* ysl = (u16*)(smem + 81920);
  float (*sums1)[256] = (float(*)[256])(smem + 98304);
  float (*sums2)[256] = (float(*)[256])(smem + 100352);

  const int b = blockIdx.y, n0 = blockIdx.x << 7;
  const int tid = threadIdx.x;
  const int wave = tid >> 6, lane = tid & 63;
  const int lo16 = lane & 15, hi4 = lane >> 4;
  const int wr = wave >> 1, wc = wave & 1;
  const int obase = wr * 64, nbase = wc * 64;

  f32x4 acc[4][4];
#pragma unroll
  for (int i = 0; i < 4; ++i)
#pragma unroll
    for (int j = 0; j < 4; ++j) acc[i][j] = (f32x4){0.f, 0.f, 0.f, 0.f};

  for (int step = 0; step < 2; ++step) {
    __syncthreads();
#pragma unroll
    for (int i = 0; i < 4; ++i) {
      int ci = i * 512 + tid;
      int o = ci >> 3, slot = ci & 7;
      size_t rowb = (size_t)o * 256 + step * 128 + ((slot ^ (o & 7)) << 4);
      char* dsth = (char*)wsh + (size_t)(i * 512 + (tid & ~63)) * 16;
      char* dstl = (char*)wsl + (size_t)(i * 512 + (tid & ~63)) * 16;
      __builtin_amdgcn_global_load_lds((const __attribute__((address_space(1))) unsigned*)((const char*)wwh + rowb),
                                       (__attribute__((address_space(3))) unsigned*)dsth, 16, 0, 0);
      __builtin_amdgcn_global_load_lds((const __attribute__((address_space(1))) unsigned*)((const char*)wwl + rowb),
                                       (__attribute__((address_space(3))) unsigned*)dstl, 16, 0, 0);
    }
#pragma unroll
    for (int i = 0; i < 2; ++i) {
      int ci = i * 512 + tid;
      int n = ci >> 3, slot = ci & 7;
      size_t rowb = ((size_t)(b * NSP + n0 + n)) * 256 + step * 128 + ((slot ^ (n & 7)) << 4);
      char* dsth = (char*)ysh + (size_t)(i * 512 + (tid & ~63)) * 16;
      char* dstl = (char*)ysl + (size_t)(i * 512 + (tid & ~63)) * 16;
      __builtin_amdgcn_global_load_lds((const __attribute__((address_space(1))) unsigned*)((const char*)yh + rowb),
                                       (__attribute__((address_space(3))) unsigned*)dsth, 16, 0, 0);
      __builtin_amdgcn_global_load_lds((const __attribute__((address_space(1))) unsigned*)((const char*)yl + rowb),
                                       (__attribute__((address_space(3))) unsigned*)dstl, 16, 0, 0);
    }
    __syncthreads();

#pragma unroll
    for (int kc = 0; kc < 2; ++kc) {
      const int sl = kc * 4 + hi4;
      s16x8 bfh[4], bfl[4];
#pragma unroll
      for (int fn = 0; fn < 4; ++fn) {
        int n = nbase + fn * 16 + lo16;
        int off = (int)n * 128 + ((sl ^ (n & 7)) << 4);
        bfh[fn] = *(const s16x8*)((const char*)ysh + off);
        bfl[fn] = *(const s16x8*)((const char*)ysl + off);
      }
#pragma unroll
      for (int fo = 0; fo < 4; ++fo) {
        int o = obase + fo * 16 + lo16;
        int off = (int)o * 128 + ((sl ^ (o & 7)) << 4);
        s16x8 afh = *(const s16x8*)((const char*)wsh + off);
        s16x8 afl = *(const s16x8*)((const char*)wsl + off);
#pragma unroll
        for (int fn = 0; fn < 4; ++fn) {
          acc[fo][fn] = __builtin_amdgcn_mfma_f32_16x16x32_bf16(afh, bfh[fn], acc[fo][fn], 0, 0, 0);
          acc[fo][fn] = __builtin_amdgcn_mfma_f32_16x16x32_bf16(afh, bfl[fn], acc[fo][fn], 0, 0, 0);
          acc[fo][fn] = __builtin_amdgcn_mfma_f32_16x16x32_bf16(afl, bfh[fn], acc[fo][fn], 0, 0, 0);
        }
      }
    }
  }

  // epilogue: bias, write wy, BN partial stats
#pragma unroll
  for (int fo = 0; fo < 4; ++fo) {
    int orow = obase + fo * 16 + hi4 * 4;
    float bv[4];
#pragma unroll
    for (int r = 0; r < 4; ++r) bv[r] = bw[orow + r];
    float ss[4] = {0.f, 0.f, 0.f, 0.f}, sq[4] = {0.f, 0.f, 0.f, 0.f};
#pragma unroll
    for (int fn = 0; fn < 4; ++fn) {
      int col = n0 + nbase + fn * 16 + lo16;
#pragma unroll
      for (int r = 0; r < 4; ++r) {
        float v = acc[fo][fn][r] + bv[r];
        wy[((size_t)(b * NC) + orow + r) * NSP + col] = v;
        ss[r] += v;
        sq[r] += v * v;
      }
    }
#pragma unroll
    for (int r = 0; r < 4; ++r) {
#pragma unroll
      for (int d = 1; d < 16; d <<= 1) {
        ss[r] += __shfl_xor(ss[r], d);
        sq[r] += __shfl_xor(sq[r], d);
      }
    }
    if (lo16 == 0) {
#pragma unroll
      for (int r = 0; r < 4; ++r) {
        sums1[wc][orow + r] = ss[r];
        sums2[wc][orow + r] = sq[r];
      }
    }
  }
  __syncthreads();
  if (tid < 256) {
    atomicAdd(&s1g[tid], sums1[0][tid] + sums1[1][tid]);
    atomicAdd(&s2g[tid], sums2[0][tid] + sums2[1][tid]);
  }
}

// ---- BN (batch stats) + affine + residual, float4 ----------------------------------
__global__ __launch_bounds__(256) void bn_res4(
    const float* __restrict__ wy, const float* __restrict__ x,
    const float* __restrict__ s1, const float* __restrict__ s2,
    const float* __restrict__ gamma, const float* __restrict__ beta,
    float* __restrict__ out)
{
  int i4 = (blockIdx.x * 256 + threadIdx.x) << 2;
  int c = (i4 >> 12) & 255;
  const float cnt = 1.f / 32768.f;
  float mean = s1[c] * cnt;
  float var = s2[c] * cnt - mean * mean;
  float inv = rsqrtf(var + 1e-5f) * gamma[c];
  float bet = beta[c];
  float4 w = *(const float4*)&wy[i4];
  float4 xv = *(const float4*)&x[i4];
  float4 o;
  o.x = (w.x - mean) * inv + bet + xv.x;
  o.y = (w.y - mean) * inv + bet + xv.y;
  o.z = (w.z - mean) * inv + bet + xv.z;
  o.w = (w.w - mean) * inv + bet + xv.w;
  *(float4*)&out[i4] = o;
}

extern "C" void kernel_launch(void* const* d_in, const int* in_sizes, int n_in,
                              void* d_out, int out_size, void* d_ws, size_t ws_size,
                              hipStream_t stream) {
  const float* x    = (const float*)d_in[0];
  const float* w_g  = (const float*)d_in[1];
  const float* b_g  = (const float*)d_in[2];
  const float* w_th = (const float*)d_in[3];
  const float* b_th = (const float*)d_in[4];
  const float* w_ph = (const float*)d_in[5];
  const float* b_ph = (const float*)d_in[6];
  const float* w_w  = (const float*)d_in[7];
  const float* b_w  = (const float*)d_in[8];
  const float* gam  = (const float*)d_in[9];
  const float* bet  = (const float*)d_in[10];
  float* out = (float*)d_out;
  char* ws = (char*)d_ws;

  u16*   xh  = (u16*)(ws + OFF_XH);
  u16*   xl  = (u16*)(ws + OFF_XL);
  u16*   thT = (u16*)(ws + OFF_THT);
  u16*   phT = (u16*)(ws + OFF_PHT);
  u16*   gp  = (u16*)(ws + OFF_GP);
  u16*   yhb = (u16*)(ws + OFF_YH);
  u16*   ylb = (u16*)(ws + OFF_YL);
  float* wy  = (float*)(ws + OFF_WY);
  u16*   wbh = (u16*)(ws + OFF_WBH);
  u16*   wbl = (u16*)(ws + OFF_WBL);
  u16*   wwh = (u16*)(ws + OFF_WWH);
  u16*   wwl = (u16*)(ws + OFF_WWL);
  float* s1  = (float*)(ws + OFF_S);
  float* s2  = s1 + 256;

  wcvt<<<dim3(512), 256, 0, stream>>>(w_g, w_th, w_ph, w_w, wbh, wbl, wwh, wwl);
  zero_stats<<<dim3(1), 512, 0, stream>>>(s1);
  xt_cvt<<<dim3(64, 4, 8), 256, 0, stream>>>(x, xh, xl);

  proj_fused<<<dim3(32, 8), 512, 0, stream>>>(xh, xl, wbh, wbl, b_g, b_th, b_ph, thT, phT, gp);

  attn_mfma<<<dim3(32, 8), 512, 0, stream>>>(thT, phT, gp, yhb, ylb);

  conv_w_mfma<<<dim3(32, 8), 512, 0, stream>>>(yhb, ylb, wwh, wwl, b_w, wy, s1, s2);

  bn_res4<<<dim3(8192), 256, 0, stream>>>(wy, x, s1, s2, gam, bet, out);
}

// Round 6
// 125.705 us; speedup vs baseline: 5.5732x; 1.0334x over previous
//
#include <hip/hip_runtime.h>
#include <hip/hip_bf16.h>

// Problem constants: B=8, C=256, Ci=128, H=W=64, N=4096, M=1024
#define NB 8
#define NC 256
#define NCI 128
#define NSP 4096
#define NM 1024

typedef float f32x4 __attribute__((ext_vector_type(4)));
typedef short s16x8 __attribute__((ext_vector_type(8)));
typedef unsigned short u16;

// Workspace layout (byte offsets, total < 64 MB)
#define OFF_XH  (0ull)              // xh bf16 [B][N][C]  16 MB (dead after proj)
#define OFF_XL  (16777216ull)       // xl bf16 [B][N][C]  16 MB (dead after proj)
#define OFF_THT (33554432ull)       // thT bf16 [B][N][Ci] 8 MB (dead after attn)
#define OFF_PHT (41943040ull)       // phT bf16 [B][M][Ci] 2 MB
#define OFF_GP  (44040192ull)       // gp  bf16 [B][Ci][M] 2 MB
#define OFF_YH  (46137344ull)       // yh  bf16 [B][N][Ci] 8 MB
#define OFF_YL  (54525952ull)       // yl  bf16 [B][N][Ci] 8 MB
#define OFF_WY  (0ull)              // wy f32 [B][C][N] 32 MB (overlays XH+XL, dead)
#define OFF_WBH (62914560ull)       // wb hi bf16 [384][256] 192 KB
#define OFF_WBL (63111168ull)       // wb lo
#define OFF_WWH (63307776ull)       // wwb hi bf16 [256][128] 64 KB
#define OFF_WWL (63373312ull)       // wwb lo
#define OFF_S   (63438848ull)       // s1[256], s2[256] f32

#define GLL(src, dst) __builtin_amdgcn_global_load_lds( \
    (const __attribute__((address_space(1))) unsigned*)(src), \
    (__attribute__((address_space(3))) unsigned*)(dst), 16, 0, 0)

__device__ __forceinline__ u16 f2bf(float f) {
  union { __hip_bfloat16 h; u16 u; } v;
  v.h = __float2bfloat16(f);
  return v.u;
}
__device__ __forceinline__ float bf2f(u16 u) {
  union { unsigned u; float f; } v;
  v.u = (unsigned)u << 16;
  return v.f;
}
__device__ __forceinline__ u16 bfmax4(u16 a, u16 b, u16 c, u16 d) {
  float v = fmaxf(fmaxf(bf2f(a), bf2f(b)), fmaxf(bf2f(c), bf2f(d)));
  return f2bf(v);
}

__global__ void zero_stats(float* s) { s[threadIdx.x] = 0.f; }

// ---- weights -> bf16 hi/lo (wb stacked: rows 0-127 g, 128-255 theta, 256-383 phi) --
__global__ __launch_bounds__(256) void wcvt(
    const float* __restrict__ wg, const float* __restrict__ wth,
    const float* __restrict__ wph, const float* __restrict__ ww,
    u16* __restrict__ wbh, u16* __restrict__ wbl,
    u16* __restrict__ wwh, u16* __restrict__ wwl)
{
  int idx = blockIdx.x * 256 + threadIdx.x;
  if (idx < 384 * 256) {
    int row = idx >> 8, k = idx & 255;
    float v = row < 128 ? wg[row * 256 + k]
            : row < 256 ? wth[(row - 128) * 256 + k]
                        : wph[(row - 256) * 256 + k];
    u16 h = f2bf(v);
    wbh[idx] = h;
    wbl[idx] = f2bf(v - bf2f(h));
  } else {
    int j = idx - 384 * 256;
    float v = ww[j];
    u16 h = f2bf(v);
    wwh[j] = h;
    wwl[j] = f2bf(v - bf2f(h));
  }
}

// ---- x [B][C][N] f32 -> xh/xl [B][N][C] bf16 hi/lo (transpose + split) -------------
__global__ __launch_bounds__(256) void xt_cvt(const float* __restrict__ x,
                                              u16* __restrict__ xh, u16* __restrict__ xl)
{
  __shared__ float t[64 * 68];
  const int n0 = blockIdx.x << 6, c0 = blockIdx.y << 6, b = blockIdx.z;
  const int tid = threadIdx.x;
  const int cl = tid >> 4, n4 = (tid & 15) << 2;
#pragma unroll
  for (int it = 0; it < 4; ++it) {
    int c = it * 16 + cl;
    float4 v = *(const float4*)&x[((size_t)(b * NC + c0 + c)) * NSP + n0 + n4];
    *(float4*)&t[c * 68 + n4] = v;
  }
  __syncthreads();
#pragma unroll
  for (int it = 0; it < 2; ++it) {
    int task = it * 256 + tid;
    int n = task >> 3, cc = (task & 7) << 3;
    u16 oh[8], ol[8];
#pragma unroll
    for (int i = 0; i < 8; ++i) {
      float v = t[(cc + i) * 68 + n];
      oh[i] = f2bf(v);
      ol[i] = f2bf(v - bf2f(oh[i]));
    }
    size_t dst = ((size_t)(b * NSP + n0 + n)) * NC + c0 + cc;
    *(s16x8*)&xh[dst] = *(s16x8*)oh;
    *(s16x8*)&xl[dst] = *(s16x8*)ol;
  }
}

// ---- fused projection: all 384 channels, 3-pass split MFMA, bias+pool+layouts ------
__global__ __launch_bounds__(512, 1) void proj_fused(
    const u16* __restrict__ xh, const u16* __restrict__ xl,
    const u16* __restrict__ wbh, const u16* __restrict__ wbl,
    const float* __restrict__ bg, const float* __restrict__ bth,
    const float* __restrict__ bph,
    u16* __restrict__ thT, u16* __restrict__ phT, u16* __restrict__ gp)
{
  __shared__ char smem[132608];
  u16* xsh = (u16*)smem;                 // [128 n][64 k]  16 KB swizzled
  u16* xsl = (u16*)(smem + 16384);       // [128 n][64 k]  16 KB
  u16* wsh = (u16*)(smem + 32768);       // [384 o][64 k]  48 KB
  u16* wsl = (u16*)(smem + 81920);       // [384 o][64 k]  48 KB
  u16* outl = (u16*)smem;                // epilogue [384][137] bf16 overlay
  float* bias = (float*)(smem + 131072); // 384 f32

  const int b = blockIdx.y, h2 = blockIdx.x;
  const int n0 = h2 << 7;
  const int tid = threadIdx.x;
  const int wave = tid >> 6, lane = tid & 63;
  const int lo16 = lane & 15, hi4 = lane >> 4;
  const int wr = wave >> 1, wc = wave & 1;
  const int obase = wr * 96, nbase = wc * 64;

  if (tid < 384)
    bias[tid] = tid < 128 ? bg[tid] : tid < 256 ? bth[tid - 128] : bph[tid - 256];

  f32x4 acc[6][4];
#pragma unroll
  for (int i = 0; i < 6; ++i)
#pragma unroll
    for (int j = 0; j < 4; ++j) acc[i][j] = (f32x4){0.f, 0.f, 0.f, 0.f};

  for (int step = 0; step < 4; ++step) {
    __syncthreads();
#pragma unroll
    for (int i = 0; i < 2; ++i) {
      int ci = i * 512 + tid;
      int n = ci >> 3, slot = ci & 7;
      size_t rowb = ((size_t)(b * NSP + n0 + n)) * 512 + step * 128 + ((slot ^ (n & 7)) << 4);
      GLL((const char*)xh + rowb, (char*)xsh + (size_t)(i * 512 + (tid & ~63)) * 16);
      GLL((const char*)xl + rowb, (char*)xsl + (size_t)(i * 512 + (tid & ~63)) * 16);
    }
#pragma unroll
    for (int i = 0; i < 6; ++i) {
      int ci = i * 512 + tid;
      int o = ci >> 3, slot = ci & 7;
      size_t rowb = (size_t)o * 512 + step * 128 + ((slot ^ (o & 7)) << 4);
      GLL((const char*)wbh + rowb, (char*)wsh + (size_t)(i * 512 + (tid & ~63)) * 16);
      GLL((const char*)wbl + rowb, (char*)wsl + (size_t)(i * 512 + (tid & ~63)) * 16);
    }
    __syncthreads();

#pragma unroll
    for (int kc = 0; kc < 2; ++kc) {
      const int sl = kc * 4 + hi4;
      s16x8 bfh[4], bfl[4];
#pragma unroll
      for (int fn = 0; fn < 4; ++fn) {
        int n = nbase + fn * 16 + lo16;
        int off = (int)n * 128 + ((sl ^ (n & 7)) << 4);
        bfh[fn] = *(const s16x8*)((const char*)xsh + off);
        bfl[fn] = *(const s16x8*)((const char*)xsl + off);
      }
      __builtin_amdgcn_s_setprio(1);
#pragma unroll
      for (int fo = 0; fo < 6; ++fo) {
        int o = obase + fo * 16 + lo16;
        int off = (int)o * 128 + ((sl ^ (o & 7)) << 4);
        s16x8 afh = *(const s16x8*)((const char*)wsh + off);
        s16x8 afl = *(const s16x8*)((const char*)wsl + off);
#pragma unroll
        for (int fn = 0; fn < 4; ++fn) {
          acc[fo][fn] = __builtin_amdgcn_mfma_f32_16x16x32_bf16(afh, bfh[fn], acc[fo][fn], 0, 0, 0);
          acc[fo][fn] = __builtin_amdgcn_mfma_f32_16x16x32_bf16(afh, bfl[fn], acc[fo][fn], 0, 0, 0);
          acc[fo][fn] = __builtin_amdgcn_mfma_f32_16x16x32_bf16(afl, bfh[fn], acc[fo][fn], 0, 0, 0);
        }
      }
      __builtin_amdgcn_s_setprio(0);
    }
  }

  __syncthreads();  // all MFMA done; staging buffers dead; outl overlays them
#pragma unroll
  for (int fo = 0; fo < 6; ++fo) {
    int orow = obase + fo * 16 + hi4 * 4;
    f32x4 bv = *(const f32x4*)&bias[orow];
#pragma unroll
    for (int fn = 0; fn < 4; ++fn) {
      int n = nbase + fn * 16 + lo16;
#pragma unroll
      for (int r = 0; r < 4; ++r)
        outl[(orow + r) * 137 + n] = f2bf(acc[fo][fn][r] + bv[r]);
    }
  }
  __syncthreads();

  // theta rows 128..255 -> thT[b][n][c]
#pragma unroll
  for (int it = 0; it < 4; ++it) {
    int task = it * 512 + tid;
    int n = task >> 4, cc = (task & 15) << 3;
    u16 o[8];
#pragma unroll
    for (int i = 0; i < 8; ++i) o[i] = outl[(128 + cc + i) * 137 + n];
    *(s16x8*)&thT[((size_t)(b * NSP + n0 + n)) * NCI + cc] = *(s16x8*)o;
  }
  // g rows 0..127, pooled -> gp[b][c][m]
  {
    int c = tid >> 2, wq = tid & 3;
    u16 o[8];
#pragma unroll
    for (int j = 0; j < 8; ++j) {
      int w2 = wq * 8 + j;
      o[j] = bfmax4(outl[c * 137 + 2 * w2], outl[c * 137 + 2 * w2 + 1],
                    outl[c * 137 + 64 + 2 * w2], outl[c * 137 + 64 + 2 * w2 + 1]);
    }
    *(s16x8*)&gp[((size_t)(b * NCI + c)) * NM + (h2 << 5) + wq * 8] = *(s16x8*)o;
  }
  // phi rows 256..383, pooled + transposed -> phT[b][m][c]
  {
    int w2 = tid >> 4, cc = (tid & 15) << 3;
    u16 o[8];
#pragma unroll
    for (int i = 0; i < 8; ++i) {
      int c = 256 + cc + i;
      o[i] = bfmax4(outl[c * 137 + 2 * w2], outl[c * 137 + 2 * w2 + 1],
                    outl[c * 137 + 64 + 2 * w2], outl[c * 137 + 64 + 2 * w2 + 1]);
    }
    *(s16x8*)&phT[((size_t)(b * NM + (h2 << 5) + w2)) * NCI + cc] = *(s16x8*)o;
  }
}

// ---- MFMA flash attention: 64 q/block, 4 waves, dbuf prefetch, 2 blocks/CU ---------
// Round-4 softmax numerics (always rescale); round-4 fragment/swizzle layout.
__global__ __launch_bounds__(256, 2) void attn_mfma(
    const u16* __restrict__ thT, const u16* __restrict__ phT,
    const u16* __restrict__ gP, u16* __restrict__ yh, u16* __restrict__ yl)
{
  __shared__ u16 phs[2][64 * 128];   // phi^T tile [m][c] dbuf (32 KB)
  __shared__ u16 gs[2][128 * 64];    // g tile [c][m] dbuf (32 KB)
  __shared__ u16 ps[4][16 * 72];     // per-wave P (9 KB)

  const int b = blockIdx.y;
  const int n0 = blockIdx.x << 6;
  const int tid = threadIdx.x;
  const int wave = tid >> 6;
  const int lane = tid & 63;
  const int lo16 = lane & 15;
  const int hi4 = lane >> 4;
  const int qbase = n0 + (wave << 4);
  const int swq = (lo16 & 7) << 4;

  s16x8 tha[4];
#pragma unroll
  for (int kc = 0; kc < 4; ++kc)
    tha[kc] = *(const s16x8*)&thT[((size_t)b * NSP + qbase + lo16) * NCI + kc * 32 + hi4 * 8];

  f32x4 yacc[8];
#pragma unroll
  for (int i = 0; i < 8; ++i) yacc[i] = (f32x4){0.f, 0.f, 0.f, 0.f};
  float m_i[4] = {-3e38f, -3e38f, -3e38f, -3e38f};
  float l_i[4] = {0.f, 0.f, 0.f, 0.f};

  auto stage = [&](int s, int m0) {
#pragma unroll
    for (int i = 0; i < 4; ++i) {      // phi tile: 1024 chunks of 16 B
      int ci = i * 256 + tid;
      int m = ci >> 4, cb = (ci & 15) << 4;
      const char* src = (const char*)phT + (((size_t)b * NM + m0 + m) << 8) + (cb ^ ((m & 7) << 4));
      GLL(src, (char*)phs[s] + (size_t)(i * 256 + (tid & ~63)) * 16);
    }
#pragma unroll
    for (int i = 0; i < 4; ++i) {      // g tile: 1024 chunks
      int ci = i * 256 + tid;
      int c = ci >> 3, mb = (ci & 7) << 4;
      const char* src = (const char*)gP + (((size_t)b * NCI + c) << 11) + m0 * 2 + (mb ^ ((c & 7) << 4));
      GLL(src, (char*)gs[s] + (size_t)(i * 256 + (tid & ~63)) * 16);
    }
  };

  stage(0, 0);
  __syncthreads();   // compiler drains vmcnt before barrier: tile 0 landed
  int cur = 0;

  for (int mt = 0; mt < 16; ++mt) {
    if (mt < 15) stage(cur ^ 1, (mt + 1) << 6);   // prefetch next tile during compute

    const u16* ph = phs[cur];
    const u16* gg = gs[cur];

    // S = theta x phi^T
    f32x4 sf[4];
#pragma unroll
    for (int ms = 0; ms < 4; ++ms) sf[ms] = (f32x4){0.f, 0.f, 0.f, 0.f};
    __builtin_amdgcn_s_setprio(1);
#pragma unroll
    for (int ms = 0; ms < 4; ++ms) {
      const int rbase = (ms * 16 + lo16) << 8;
#pragma unroll
      for (int kc = 0; kc < 4; ++kc) {
        s16x8 bp = *(const s16x8*)((const char*)ph + rbase + ((kc * 64 + hi4 * 16) ^ swq));
        sf[ms] = __builtin_amdgcn_mfma_f32_16x16x32_bf16(tha[kc], bp, sf[ms], 0, 0, 0);
      }
    }
    __builtin_amdgcn_s_setprio(0);

    // online softmax (round-4 numerics: always rescale)
    float scv[4];
#pragma unroll
    for (int r = 0; r < 4; ++r) {
      float v = fmaxf(fmaxf(sf[0][r], sf[1][r]), fmaxf(sf[2][r], sf[3][r]));
      v = fmaxf(v, __shfl_xor(v, 1));
      v = fmaxf(v, __shfl_xor(v, 2));
      v = fmaxf(v, __shfl_xor(v, 4));
      v = fmaxf(v, __shfl_xor(v, 8));
      float mn = fmaxf(m_i[r], v);
      float sc = __expf(m_i[r] - mn);
      float rs = 0.f;
#pragma unroll
      for (int ms = 0; ms < 4; ++ms) {
        float e = __expf(sf[ms][r] - mn);
        sf[ms][r] = e;
        rs += e;
      }
      rs += __shfl_xor(rs, 1);
      rs += __shfl_xor(rs, 2);
      rs += __shfl_xor(rs, 4);
      rs += __shfl_xor(rs, 8);
      l_i[r] = l_i[r] * sc + rs;
      m_i[r] = mn;
      scv[r] = sc;
    }
#pragma unroll
    for (int ct = 0; ct < 8; ++ct)
#pragma unroll
      for (int r = 0; r < 4; ++r) yacc[ct][r] *= scv[r];

    // P (bf16) -> per-wave LDS, read back as A-fragments
    u16* pw = ps[wave];
#pragma unroll
    for (int ms = 0; ms < 4; ++ms)
#pragma unroll
      for (int r = 0; r < 4; ++r)
        pw[(hi4 * 4 + r) * 72 + ms * 16 + lo16] = f2bf(sf[ms][r]);
    asm volatile("s_waitcnt lgkmcnt(0)" ::: "memory");

    s16x8 pa[2];
#pragma unroll
    for (int km = 0; km < 2; ++km)
      pa[km] = *(const s16x8*)((const char*)pw + lo16 * 144 + km * 64 + hi4 * 16);

    // PV
    __builtin_amdgcn_s_setprio(1);
#pragma unroll
    for (int ct = 0; ct < 8; ++ct) {
      const int rb = (ct * 16 + lo16) << 7;
#pragma unroll
      for (int km = 0; km < 2; ++km) {
        s16x8 bg = *(const s16x8*)((const char*)gg + rb + ((km * 64 + hi4 * 16) ^ swq));
        yacc[ct] = __builtin_amdgcn_mfma_f32_16x16x32_bf16(pa[km], bg, yacc[ct], 0, 0, 0);
      }
    }
    __builtin_amdgcn_s_setprio(0);

    __syncthreads();   // drains prefetch loads; all waves done with buf[cur]
    cur ^= 1;
  }

#pragma unroll
  for (int r = 0; r < 4; ++r) {
    float inv = 1.f / l_i[r];
    size_t row = ((size_t)b * NSP + qbase + hi4 * 4 + r) * NCI;
#pragma unroll
    for (int ct = 0; ct < 8; ++ct) {
      float v = yacc[ct][r] * inv;
      u16 h = f2bf(v);
      yh[row + ct * 16 + lo16] = h;
      yl[row + ct * 16 + lo16] = f2bf(v - bf2f(h));
    }
  }
}

// ---- W conv 3-pass split MFMA + fused BN stats; wy f32 (round-4 numerics) ----------
__global__ __launch_bounds__(512, 1) void conv_w_mfma(
    const u16* __restrict__ yh, const u16* __restrict__ yl,
    const u16* __restrict__ wwh, const u16* __restrict__ wwl,
    const float* __restrict__ bw, float* __restrict__ wy,
    float* __restrict__ s1g, float* __restrict__ s2g)
{
  __shared__ char smem[102400];
  u16* wsh = (u16*)smem;                  // [256 o][64 k] 32 KB swizzled
  u16* wsl = (u16*)(smem + 32768);
  u16* ysh = (u16*)(smem + 65536);        // [128 n][64 k] 16 KB
  u16* ysl = (u16*)(smem + 81920);
  float (*sums1)[256] = (float(*)[256])(smem + 98304);
  float (*sums2)[256] = (float(*)[256])(smem + 100352);

  const int b = blockIdx.y, n0 = blockIdx.x << 7;
  const int tid = threadIdx.x;
  const int wave = tid >> 6, lane = tid & 63;
  const int lo16 = lane & 15, hi4 = lane >> 4;
  const int wr = wave >> 1, wc = wave & 1;
  const int obase = wr * 64, nbase = wc * 64;

  f32x4 acc[4][4];
#pragma unroll
  for (int i = 0; i < 4; ++i)
#pragma unroll
    for (int j = 0; j < 4; ++j) acc[i][j] = (f32x4){0.f, 0.f, 0.f, 0.f};

  for (int step = 0; step < 2; ++step) {
    __syncthreads();
#pragma unroll
    for (int i = 0; i < 4; ++i) {
      int ci = i * 512 + tid;
      int o = ci >> 3, slot = ci & 7;
      size_t rowb = (size_t)o * 256 + step * 128 + ((slot ^ (o & 7)) << 4);
      GLL((const char*)wwh + rowb, (char*)wsh + (size_t)(i * 512 + (tid & ~63)) * 16);
      GLL((const char*)wwl + rowb, (char*)wsl + (size_t)(i * 512 + (tid & ~63)) * 16);
    }
#pragma unroll
    for (int i = 0; i < 2; ++i) {
      int ci = i * 512 + tid;
      int n = ci >> 3, slot = ci & 7;
      size_t rowb = ((size_t)(b * NSP + n0 + n)) * 256 + step * 128 + ((slot ^ (n & 7)) << 4);
      GLL((const char*)yh + rowb, (char*)ysh + (size_t)(i * 512 + (tid & ~63)) * 16);
      GLL((const char*)yl + rowb, (char*)ysl + (size_t)(i * 512 + (tid & ~63)) * 16);
    }
    __syncthreads();

#pragma unroll
    for (int kc = 0; kc < 2; ++kc) {
      const int sl = kc * 4 + hi4;
      s16x8 bfh[4], bfl[4];
#pragma unroll
      for (int fn = 0; fn < 4; ++fn) {
        int n = nbase + fn * 16 + lo16;
        int off = (int)n * 128 + ((sl ^ (n & 7)) << 4);
        bfh[fn] = *(const s16x8*)((const char*)ysh + off);
        bfl[fn] = *(const s16x8*)((const char*)ysl + off);
      }
      __builtin_amdgcn_s_setprio(1);
#pragma unroll
      for (int fo = 0; fo < 4; ++fo) {
        int o = obase + fo * 16 + lo16;
        int off = (int)o * 128 + ((sl ^ (o & 7)) << 4);
        s16x8 afh = *(const s16x8*)((const char*)wsh + off);
        s16x8 afl = *(const s16x8*)((const char*)wsl + off);
#pragma unroll
        for (int fn = 0; fn < 4; ++fn) {
          acc[fo][fn] = __builtin_amdgcn_mfma_f32_16x16x32_bf16(afh, bfh[fn], acc[fo][fn], 0, 0, 0);
          acc[fo][fn] = __builtin_amdgcn_mfma_f32_16x16x32_bf16(afh, bfl[fn], acc[fo][fn], 0, 0, 0);
          acc[fo][fn] = __builtin_amdgcn_mfma_f32_16x16x32_bf16(afl, bfh[fn], acc[fo][fn], 0, 0, 0);
        }
      }
      __builtin_amdgcn_s_setprio(0);
    }
  }

  // epilogue: bias, write wy (f32), BN partial stats
#pragma unroll
  for (int fo = 0; fo < 4; ++fo) {
    int orow = obase + fo * 16 + hi4 * 4;
    float bv[4];
#pragma unroll
    for (int r = 0; r < 4; ++r) bv[r] = bw[orow + r];
    float ss[4] = {0.f, 0.f, 0.f, 0.f}, sq[4] = {0.f, 0.f, 0.f, 0.f};
#pragma unroll
    for (int fn = 0; fn < 4; ++fn) {
      int col = n0 + nbase + fn * 16 + lo16;
#pragma unroll
      for (int r = 0; r < 4; ++r) {
        float v = acc[fo][fn][r] + bv[r];
        wy[((size_t)(b * NC) + orow + r) * NSP + col] = v;
        ss[r] += v;
        sq[r] += v * v;
      }
    }
#pragma unroll
    for (int r = 0; r < 4; ++r) {
#pragma unroll
      for (int d = 1; d < 16; d <<= 1) {
        ss[r] += __shfl_xor(ss[r], d);
        sq[r] += __shfl_xor(sq[r], d);
      }
    }
    if (lo16 == 0) {
#pragma unroll
      for (int r = 0; r < 4; ++r) {
        sums1[wc][orow + r] = ss[r];
        sums2[wc][orow + r] = sq[r];
      }
    }
  }
  __syncthreads();
  if (tid < 256) {
    atomicAdd(&s1g[tid], sums1[0][tid] + sums1[1][tid]);
    atomicAdd(&s2g[tid], sums2[0][tid] + sums2[1][tid]);
  }
}

// ---- BN (batch stats) + affine + residual, float4 ----------------------------------
__global__ __launch_bounds__(256) void bn_res4(
    const float* __restrict__ wy, const float* __restrict__ x,
    const float* __restrict__ s1, const float* __restrict__ s2,
    const float* __restrict__ gamma, const float* __restrict__ beta,
    float* __restrict__ out)
{
  int i4 = (blockIdx.x * 256 + threadIdx.x) << 2;
  int c = (i4 >> 12) & 255;
  const float cnt = 1.f / 32768.f;
  float mean = s1[c] * cnt;
  float var = s2[c] * cnt - mean * mean;
  float inv = rsqrtf(var + 1e-5f) * gamma[c];
  float bet = beta[c];
  float4 w = *(const float4*)&wy[i4];
  float4 xv = *(const float4*)&x[i4];
  float4 o;
  o.x = (w.x - mean) * inv + bet + xv.x;
  o.y = (w.y - mean) * inv + bet + xv.y;
  o.z = (w.z - mean) * inv + bet + xv.z;
  o.w = (w.w - mean) * inv + bet + xv.w;
  *(float4*)&out[i4] = o;
}

extern "C" void kernel_launch(void* const* d_in, const int* in_sizes, int n_in,
                              void* d_out, int out_size, void* d_ws, size_t ws_size,
                              hipStream_t stream) {
  const float* x    = (const float*)d_in[0];
  const float* w_g  = (const float*)d_in[1];
  const float* b_g  = (const float*)d_in[2];
  const float* w_th = (const float*)d_in[3];
  const float* b_th = (const float*)d_in[4];
  const float* w_ph = (const float*)d_in[5];
  const float* b_ph = (const float*)d_in[6];
  const float* w_w  = (const float*)d_in[7];
  const float* b_w  = (const float*)d_in[8];
  const float* gam  = (const float*)d_in[9];
  const float* bet  = (const float*)d_in[10];
  float* out = (float*)d_out;
  char* ws = (char*)d_ws;

  u16*   xh  = (u16*)(ws + OFF_XH);
  u16*   xl  = (u16*)(ws + OFF_XL);
  u16*   thT = (u16*)(ws + OFF_THT);
  u16*   phT = (u16*)(ws + OFF_PHT);
  u16*   gp  = (u16*)(ws + OFF_GP);
  u16*   yhb = (u16*)(ws + OFF_YH);
  u16*   ylb = (u16*)(ws + OFF_YL);
  float* wy  = (float*)(ws + OFF_WY);
  u16*   wbh = (u16*)(ws + OFF_WBH);
  u16*   wbl = (u16*)(ws + OFF_WBL);
  u16*   wwh = (u16*)(ws + OFF_WWH);
  u16*   wwl = (u16*)(ws + OFF_WWL);
  float* s1  = (float*)(ws + OFF_S);
  float* s2  = s1 + 256;

  wcvt<<<dim3(512), 256, 0, stream>>>(w_g, w_th, w_ph, w_w, wbh, wbl, wwh, wwl);
  zero_stats<<<dim3(1), 512, 0, stream>>>(s1);
  xt_cvt<<<dim3(64, 4, 8), 256, 0, stream>>>(x, xh, xl);

  proj_fused<<<dim3(32, 8), 512, 0, stream>>>(xh, xl, wbh, wbl, b_g, b_th, b_ph, thT, phT, gp);

  attn_mfma<<<dim3(64, 8), 256, 0, stream>>>(thT, phT, gp, yhb, ylb);

  conv_w_mfma<<<dim3(32, 8), 512, 0, stream>>>(yhb, ylb, wwh, wwl, b_w, wy, s1, s2);

  bn_res4<<<dim3(8192), 256, 0, stream>>>(wy, x, s1, s2, gam, bet, out);
}

// Round 7
// 119.571 us; speedup vs baseline: 5.8591x; 1.0513x over previous
//
#include <hip/hip_runtime.h>
#include <hip/hip_bf16.h>

// Problem constants: B=8, C=256, Ci=128, H=W=64, N=4096, M=1024
#define NB 8
#define NC 256
#define NCI 128
#define NSP 4096
#define NM 1024

typedef float f32x4 __attribute__((ext_vector_type(4)));
typedef float f32x16 __attribute__((ext_vector_type(16)));
typedef short s16x8 __attribute__((ext_vector_type(8)));
typedef unsigned short u16;

// Workspace layout (byte offsets, total < 64 MB)
#define OFF_XH  (0ull)              // xh bf16 [B][N][C]  16 MB (dead after proj)
#define OFF_XL  (16777216ull)       // xl bf16 [B][N][C]  16 MB (dead after proj)
#define OFF_THT (33554432ull)       // thT bf16 [B][N][Ci] 8 MB (dead after attn)
#define OFF_PHT (41943040ull)       // phT bf16 [B][M][Ci] 2 MB
#define OFF_GP  (44040192ull)       // gp  bf16 [B][Ci][M] 2 MB
#define OFF_YH  (46137344ull)       // yh  bf16 [B][N][Ci] 8 MB
#define OFF_YL  (54525952ull)       // yl  bf16 [B][N][Ci] 8 MB
#define OFF_WY  (0ull)              // wy f32 [B][C][N] 32 MB (overlays XH+XL, dead)
#define OFF_WBH (62914560ull)       // wb hi bf16 [384][256] 192 KB
#define OFF_WBL (63111168ull)       // wb lo
#define OFF_WWH (63307776ull)       // wwb hi bf16 [256][128] 64 KB
#define OFF_WWL (63373312ull)       // wwb lo
#define OFF_S   (63438848ull)       // s1[256], s2[256] f32

#define GLL(src, dst) __builtin_amdgcn_global_load_lds( \
    (const __attribute__((address_space(1))) unsigned*)(src), \
    (__attribute__((address_space(3))) unsigned*)(dst), 16, 0, 0)

__device__ __forceinline__ u16 f2bf(float f) {
  union { __hip_bfloat16 h; u16 u; } v;
  v.h = __float2bfloat16(f);
  return v.u;
}
__device__ __forceinline__ float bf2f(u16 u) {
  union { unsigned u; float f; } v;
  v.u = (unsigned)u << 16;
  return v.f;
}
__device__ __forceinline__ u16 bfmax4(u16 a, u16 b, u16 c, u16 d) {
  float v = fmaxf(fmaxf(bf2f(a), bf2f(b)), fmaxf(bf2f(c), bf2f(d)));
  return f2bf(v);
}
__device__ __forceinline__ unsigned cvtpk(float lo, float hi) {
  unsigned r;
  asm volatile("v_cvt_pk_bf16_f32 %0, %1, %2" : "=v"(r) : "v"(lo), "v"(hi));
  return r;
}

__global__ void zero_stats(float* s) { s[threadIdx.x] = 0.f; }

// ---- weights -> bf16 hi/lo (wb stacked: rows 0-127 g, 128-255 theta, 256-383 phi) --
__global__ __launch_bounds__(256) void wcvt(
    const float* __restrict__ wg, const float* __restrict__ wth,
    const float* __restrict__ wph, const float* __restrict__ ww,
    u16* __restrict__ wbh, u16* __restrict__ wbl,
    u16* __restrict__ wwh, u16* __restrict__ wwl)
{
  int idx = blockIdx.x * 256 + threadIdx.x;
  if (idx < 384 * 256) {
    int row = idx >> 8, k = idx & 255;
    float v = row < 128 ? wg[row * 256 + k]
            : row < 256 ? wth[(row - 128) * 256 + k]
                        : wph[(row - 256) * 256 + k];
    u16 h = f2bf(v);
    wbh[idx] = h;
    wbl[idx] = f2bf(v - bf2f(h));
  } else {
    int j = idx - 384 * 256;
    float v = ww[j];
    u16 h = f2bf(v);
    wwh[j] = h;
    wwl[j] = f2bf(v - bf2f(h));
  }
}

// ---- x [B][C][N] f32 -> xh/xl [B][N][C] bf16 hi/lo (transpose + split) -------------
__global__ __launch_bounds__(256) void xt_cvt(const float* __restrict__ x,
                                              u16* __restrict__ xh, u16* __restrict__ xl)
{
  __shared__ float t[64 * 68];
  const int n0 = blockIdx.x << 6, c0 = blockIdx.y << 6, b = blockIdx.z;
  const int tid = threadIdx.x;
  const int cl = tid >> 4, n4 = (tid & 15) << 2;
#pragma unroll
  for (int it = 0; it < 4; ++it) {
    int c = it * 16 + cl;
    float4 v = *(const float4*)&x[((size_t)(b * NC + c0 + c)) * NSP + n0 + n4];
    *(float4*)&t[c * 68 + n4] = v;
  }
  __syncthreads();
#pragma unroll
  for (int it = 0; it < 2; ++it) {
    int task = it * 256 + tid;
    int n = task >> 3, cc = (task & 7) << 3;
    u16 oh[8], ol[8];
#pragma unroll
    for (int i = 0; i < 8; ++i) {
      float v = t[(cc + i) * 68 + n];
      oh[i] = f2bf(v);
      ol[i] = f2bf(v - bf2f(oh[i]));
    }
    size_t dst = ((size_t)(b * NSP + n0 + n)) * NC + c0 + cc;
    *(s16x8*)&xh[dst] = *(s16x8*)oh;
    *(s16x8*)&xl[dst] = *(s16x8*)ol;
  }
}

// ---- fused projection: all 384 channels, 3-pass split MFMA, bias+pool+layouts ------
__global__ __launch_bounds__(512, 1) void proj_fused(
    const u16* __restrict__ xh, const u16* __restrict__ xl,
    const u16* __restrict__ wbh, const u16* __restrict__ wbl,
    const float* __restrict__ bg, const float* __restrict__ bth,
    const float* __restrict__ bph,
    u16* __restrict__ thT, u16* __restrict__ phT, u16* __restrict__ gp)
{
  __shared__ char smem[132608];
  u16* xsh = (u16*)smem;                 // [128 n][64 k]  16 KB swizzled
  u16* xsl = (u16*)(smem + 16384);       // [128 n][64 k]  16 KB
  u16* wsh = (u16*)(smem + 32768);       // [384 o][64 k]  48 KB
  u16* wsl = (u16*)(smem + 81920);       // [384 o][64 k]  48 KB
  u16* outl = (u16*)smem;                // epilogue [384][137] bf16 overlay
  float* bias = (float*)(smem + 131072); // 384 f32

  const int b = blockIdx.y, h2 = blockIdx.x;
  const int n0 = h2 << 7;
  const int tid = threadIdx.x;
  const int wave = tid >> 6, lane = tid & 63;
  const int lo16 = lane & 15, hi4 = lane >> 4;
  const int wr = wave >> 1, wc = wave & 1;
  const int obase = wr * 96, nbase = wc * 64;

  if (tid < 384)
    bias[tid] = tid < 128 ? bg[tid] : tid < 256 ? bth[tid - 128] : bph[tid - 256];

  f32x4 acc[6][4];
#pragma unroll
  for (int i = 0; i < 6; ++i)
#pragma unroll
    for (int j = 0; j < 4; ++j) acc[i][j] = (f32x4){0.f, 0.f, 0.f, 0.f};

  for (int step = 0; step < 4; ++step) {
    __syncthreads();
#pragma unroll
    for (int i = 0; i < 2; ++i) {
      int ci = i * 512 + tid;
      int n = ci >> 3, slot = ci & 7;
      size_t rowb = ((size_t)(b * NSP + n0 + n)) * 512 + step * 128 + ((slot ^ (n & 7)) << 4);
      GLL((const char*)xh + rowb, (char*)xsh + (size_t)(i * 512 + (tid & ~63)) * 16);
      GLL((const char*)xl + rowb, (char*)xsl + (size_t)(i * 512 + (tid & ~63)) * 16);
    }
#pragma unroll
    for (int i = 0; i < 6; ++i) {
      int ci = i * 512 + tid;
      int o = ci >> 3, slot = ci & 7;
      size_t rowb = (size_t)o * 512 + step * 128 + ((slot ^ (o & 7)) << 4);
      GLL((const char*)wbh + rowb, (char*)wsh + (size_t)(i * 512 + (tid & ~63)) * 16);
      GLL((const char*)wbl + rowb, (char*)wsl + (size_t)(i * 512 + (tid & ~63)) * 16);
    }
    __syncthreads();

#pragma unroll
    for (int kc = 0; kc < 2; ++kc) {
      const int sl = kc * 4 + hi4;
      s16x8 bfh[4], bfl[4];
#pragma unroll
      for (int fn = 0; fn < 4; ++fn) {
        int n = nbase + fn * 16 + lo16;
        int off = (int)n * 128 + ((sl ^ (n & 7)) << 4);
        bfh[fn] = *(const s16x8*)((const char*)xsh + off);
        bfl[fn] = *(const s16x8*)((const char*)xsl + off);
      }
      __builtin_amdgcn_s_setprio(1);
#pragma unroll
      for (int fo = 0; fo < 6; ++fo) {
        int o = obase + fo * 16 + lo16;
        int off = (int)o * 128 + ((sl ^ (o & 7)) << 4);
        s16x8 afh = *(const s16x8*)((const char*)wsh + off);
        s16x8 afl = *(const s16x8*)((const char*)wsl + off);
#pragma unroll
        for (int fn = 0; fn < 4; ++fn) {
          acc[fo][fn] = __builtin_amdgcn_mfma_f32_16x16x32_bf16(afh, bfh[fn], acc[fo][fn], 0, 0, 0);
          acc[fo][fn] = __builtin_amdgcn_mfma_f32_16x16x32_bf16(afh, bfl[fn], acc[fo][fn], 0, 0, 0);
          acc[fo][fn] = __builtin_amdgcn_mfma_f32_16x16x32_bf16(afl, bfh[fn], acc[fo][fn], 0, 0, 0);
        }
      }
      __builtin_amdgcn_s_setprio(0);
    }
  }

  __syncthreads();  // all MFMA done; staging buffers dead; outl overlays them
#pragma unroll
  for (int fo = 0; fo < 6; ++fo) {
    int orow = obase + fo * 16 + hi4 * 4;
    f32x4 bv = *(const f32x4*)&bias[orow];
#pragma unroll
    for (int fn = 0; fn < 4; ++fn) {
      int n = nbase + fn * 16 + lo16;
#pragma unroll
      for (int r = 0; r < 4; ++r)
        outl[(orow + r) * 137 + n] = f2bf(acc[fo][fn][r] + bv[r]);
    }
  }
  __syncthreads();

  // theta rows 128..255 -> thT[b][n][c]
#pragma unroll
  for (int it = 0; it < 4; ++it) {
    int task = it * 512 + tid;
    int n = task >> 4, cc = (task & 15) << 3;
    u16 o[8];
#pragma unroll
    for (int i = 0; i < 8; ++i) o[i] = outl[(128 + cc + i) * 137 + n];
    *(s16x8*)&thT[((size_t)(b * NSP + n0 + n)) * NCI + cc] = *(s16x8*)o;
  }
  // g rows 0..127, pooled -> gp[b][c][m]
  {
    int c = tid >> 2, wq = tid & 3;
    u16 o[8];
#pragma unroll
    for (int j = 0; j < 8; ++j) {
      int w2 = wq * 8 + j;
      o[j] = bfmax4(outl[c * 137 + 2 * w2], outl[c * 137 + 2 * w2 + 1],
                    outl[c * 137 + 64 + 2 * w2], outl[c * 137 + 64 + 2 * w2 + 1]);
    }
    *(s16x8*)&gp[((size_t)(b * NCI + c)) * NM + (h2 << 5) + wq * 8] = *(s16x8*)o;
  }
  // phi rows 256..383, pooled + transposed -> phT[b][m][c]
  {
    int w2 = tid >> 4, cc = (tid & 15) << 3;
    u16 o[8];
#pragma unroll
    for (int i = 0; i < 8; ++i) {
      int c = 256 + cc + i;
      o[i] = bfmax4(outl[c * 137 + 2 * w2], outl[c * 137 + 2 * w2 + 1],
                    outl[c * 137 + 64 + 2 * w2], outl[c * 137 + 64 + 2 * w2 + 1]);
    }
    *(s16x8*)&phT[((size_t)(b * NM + (h2 << 5) + w2)) * NCI + cc] = *(s16x8*)o;
  }
}

// ---- MFMA flash attention: 32x32 swapped operands, in-register softmax -------------
// 4 waves x 32q = 128 q/block, grid (32, 8). KVBLK=64, dbuf global_load_lds staging.
// QK^T: D[m][q] = mfma(A=phi[m][c], B=theta^T[c][q]) -> col = q = lane&31.
// PV:   D[c][q] = mfma(A=g[c][m],  B=P^T[m][q])      -> col = q (lane-local rescale).
__global__ __launch_bounds__(256, 1) void attn_mfma(
    const u16* __restrict__ thT, const u16* __restrict__ phT,
    const u16* __restrict__ gP, u16* __restrict__ yh, u16* __restrict__ yl)
{
  __shared__ char smem[65536];   // phs dbuf 2x16KB | gs dbuf 2x16KB; bounce overlays

  const int b = blockIdx.y;
  const int n0 = blockIdx.x << 7;     // 128 queries per block
  const int tid = threadIdx.x;
  const int wave = tid >> 6;
  const int lane = tid & 63;
  const int l31 = lane & 31;
  const int hi1 = lane >> 5;
  const int qbase = n0 + (wave << 5); // 32 q per wave
  const int swl = (l31 & 7) << 4;

  // theta B-fragments in registers: B[k=c][col=q], k = kc*16 + hi1*8 + j
  s16x8 thb[8];
  {
    const u16* tr = &thT[((size_t)b * NSP + qbase + l31) * NCI + hi1 * 8];
#pragma unroll
    for (int kc = 0; kc < 8; ++kc) thb[kc] = *(const s16x8*)&tr[kc * 16];
  }

  f32x16 yacc[4];
#pragma unroll
  for (int ct = 0; ct < 4; ++ct) yacc[ct] = (f32x16)0.f;
  float m_i = -3e38f, l_i = 0.f;

  auto stage = [&](int s, int m0) {
    char* pdst = smem + s * 16384;
    char* gdst = smem + 32768 + s * 16384;
#pragma unroll
    for (int i = 0; i < 4; ++i) {      // phi^T tile [64 m][128 c]: 1024 chunks
      int ci = i * 256 + tid;
      int m = ci >> 4, cb = (ci & 15) << 4;
      const char* src = (const char*)phT + (((size_t)b * NM + m0 + m) << 8) + (cb ^ ((m & 7) << 4));
      GLL(src, pdst + (size_t)(i * 256 + (tid & ~63)) * 16);
    }
#pragma unroll
    for (int i = 0; i < 4; ++i) {      // g tile [128 c][64 m]: 1024 chunks
      int ci = i * 256 + tid;
      int c = ci >> 3, mb = (ci & 7) << 4;
      const char* src = (const char*)gP + (((size_t)b * NCI + c) << 11) + m0 * 2 + (mb ^ ((c & 7) << 4));
      GLL(src, gdst + (size_t)(i * 256 + (tid & ~63)) * 16);
    }
  };

  stage(0, 0);
  __syncthreads();
  int cur = 0;

  for (int mt = 0; mt < 16; ++mt) {
    if (mt < 15) stage(cur ^ 1, (mt + 1) << 6);
    const char* ph = smem + cur * 16384;
    const char* gg = smem + 32768 + cur * 16384;

    // QK^T: s0 = rows m 0..31, s1 = rows m 32..63 (lane holds col q=l31,
    // rows m_local = (reg&3) + 8*(reg>>2) + 4*hi1)
    f32x16 s0 = (f32x16)0.f, s1 = (f32x16)0.f;
    __builtin_amdgcn_s_setprio(1);
#pragma unroll
    for (int kc = 0; kc < 8; ++kc) {
      int cofs = (kc * 32 + hi1 * 16);
      s16x8 a0 = *(const s16x8*)(ph + l31 * 256 + (cofs ^ swl));
      s16x8 a1 = *(const s16x8*)(ph + (32 + l31) * 256 + (cofs ^ swl));
      s0 = __builtin_amdgcn_mfma_f32_32x32x16_bf16(a0, thb[kc], s0, 0, 0, 0);
      s1 = __builtin_amdgcn_mfma_f32_32x32x16_bf16(a1, thb[kc], s1, 0, 0, 0);
    }
    __builtin_amdgcn_s_setprio(0);

    // online softmax: lane holds 32 S values for its q; partner lane^32 holds other 32
    float pm = s0[0];
#pragma unroll
    for (int i = 1; i < 16; ++i) pm = fmaxf(pm, s0[i]);
#pragma unroll
    for (int i = 0; i < 16; ++i) pm = fmaxf(pm, s1[i]);
    pm = fmaxf(pm, __shfl_xor(pm, 32));
    float mn = fmaxf(m_i, pm);
    float sc = __expf(m_i - mn);
    float rs = 0.f;
#pragma unroll
    for (int i = 0; i < 16; ++i) { s0[i] = __expf(s0[i] - mn); rs += s0[i]; }
#pragma unroll
    for (int i = 0; i < 16; ++i) { s1[i] = __expf(s1[i] - mn); rs += s1[i]; }
    rs += __shfl_xor(rs, 32);
    l_i = l_i * sc + rs;
    m_i = mn;
#pragma unroll
    for (int ct = 0; ct < 4; ++ct)
#pragma unroll
      for (int i = 0; i < 16; ++i) yacc[ct][i] *= sc;

    // P^T B-fragments in-register: cvt_pk + permlane32_swap (T12)
    s16x8 pb[4];
#pragma unroll
    for (int km = 0; km < 4; ++km) {
      int r0 = (km & 1) * 8;
      unsigned X0, X1, X2, X3;
      if (km < 2) {
        X0 = cvtpk(s0[r0 + 0], s0[r0 + 1]);
        X1 = cvtpk(s0[r0 + 2], s0[r0 + 3]);
        X2 = cvtpk(s0[r0 + 4], s0[r0 + 5]);
        X3 = cvtpk(s0[r0 + 6], s0[r0 + 7]);
      } else {
        X0 = cvtpk(s1[r0 + 0], s1[r0 + 1]);
        X1 = cvtpk(s1[r0 + 2], s1[r0 + 3]);
        X2 = cvtpk(s1[r0 + 4], s1[r0 + 5]);
        X3 = cvtpk(s1[r0 + 6], s1[r0 + 7]);
      }
      asm volatile("v_permlane32_swap_b32 %0, %1" : "+v"(X0), "+v"(X2));
      asm volatile("v_permlane32_swap_b32 %0, %1" : "+v"(X1), "+v"(X3));
      unsigned d[4] = {X0, X1, X2, X3};
      pb[km] = *(s16x8*)d;
    }

    // PV: yacc[ct] (cols q, rows c = ct*32 + crow) += g-frag x P^T-frag
    __builtin_amdgcn_s_setprio(1);
#pragma unroll
    for (int ct = 0; ct < 4; ++ct) {
      const char* grow = gg + (ct * 32 + l31) * 128;
#pragma unroll
      for (int km = 0; km < 4; ++km) {
        s16x8 ga = *(const s16x8*)(grow + ((km * 32 + hi1 * 16) ^ swl));
        yacc[ct] = __builtin_amdgcn_mfma_f32_32x32x16_bf16(ga, pb[km], yacc[ct], 0, 0, 0);
      }
    }
    __builtin_amdgcn_s_setprio(0);

    __syncthreads();   // drains prefetch; all waves done with buf[cur]
    cur ^= 1;
  }

  // normalize
  float inv = 1.f / l_i;
#pragma unroll
  for (int ct = 0; ct < 4; ++ct)
#pragma unroll
    for (int i = 0; i < 16; ++i) yacc[ct][i] *= inv;

  // epilogue: LDS bounce (staging buffers dead) -> coalesced yh/yl writes
  u16* bounce = (u16*)smem;   // [4 waves][32 q][stride 132]
  const int qq = lane >> 1, c0 = (lane & 1) << 6;
#pragma unroll
  for (int pass = 0; pass < 2; ++pass) {
    __syncthreads();
#pragma unroll
    for (int ct = 0; ct < 4; ++ct) {
#pragma unroll
      for (int rp = 0; rp < 8; ++rp) {
        int r = rp * 2;
        int c = ct * 32 + (r & 3) + 8 * (r >> 2) + 4 * hi1;
        float v0 = yacc[ct][r], v1 = yacc[ct][r + 1];
        u16 h0 = f2bf(v0), h1 = f2bf(v1);
        u16 w0 = h0, w1 = h1;
        if (pass) { w0 = f2bf(v0 - bf2f(h0)); w1 = f2bf(v1 - bf2f(h1)); }
        *(unsigned*)&bounce[wave * 4224 + l31 * 132 + c] = (unsigned)w0 | ((unsigned)w1 << 16);
      }
    }
    __syncthreads();
    u16* dst = pass ? yl : yh;
    size_t row = ((size_t)b * NSP + qbase + qq) * NCI + c0;
#pragma unroll
    for (int k = 0; k < 8; ++k)
      *(s16x8*)&dst[row + k * 8] = *(const s16x8*)&bounce[wave * 4224 + qq * 132 + c0 + k * 8];
  }
}

// ---- W conv 3-pass split MFMA + fused BN stats; wy f32 -----------------------------
__global__ __launch_bounds__(512, 1) void conv_w_mfma(
    const u16* __restrict__ yh, const u16* __restrict__ yl,
    const u16* __restrict__ wwh, const u16* __restrict__ wwl,
    const float* __restrict__ bw, float* __restrict__ wy,
    float* __restrict__ s1g, float* __restrict__ s2g)
{
  __shared__ char smem[102400];
  u16* wsh = (u16*)smem;                  // [256 o][64 k] 32 KB swizzled
  u16* wsl = (u16*)(smem + 32768);
  u16* ysh = (u16*)(smem + 65536);        // [128 n][64 k] 16 KB
  u16* ysl = (u16*)(smem + 81920);
  float (*sums1)[256] = (float(*)[256])(smem + 98304);
  float (*sums2)[256] = (float(*)[256])(smem + 100352);

  const int b = blockIdx.y, n0 = blockIdx.x << 7;
  const int tid = threadIdx.x;
  const int wave = tid >> 6, lane = tid & 63;
  const int lo16 = lane & 15, hi4 = lane >> 4;
  const int wr = wave >> 1, wc = wave & 1;
  const int obase = wr * 64, nbase = wc * 64;

  f32x4 acc[4][4];
#pragma unroll
  for (int i = 0; i < 4; ++i)
#pragma unroll
    for (int j = 0; j < 4; ++j) acc[i][j] = (f32x4){0.f, 0.f, 0.f, 0.f};

  for (int step = 0; step < 2; ++step) {
    __syncthreads();
#pragma unroll
    for (int i = 0; i < 4; ++i) {
      int ci = i * 512 + tid;
      int o = ci >> 3, slot = ci & 7;
      size_t rowb = (size_t)o * 256 + step * 128 + ((slot ^ (o & 7)) << 4);
      GLL((const char*)wwh + rowb, (char*)wsh + (size_t)(i * 512 + (tid & ~63)) * 16);
      GLL((const char*)wwl + rowb, (char*)wsl + (size_t)(i * 512 + (tid & ~63)) * 16);
    }
#pragma unroll
    for (int i = 0; i < 2; ++i) {
      int ci = i * 512 + tid;
      int n = ci >> 3, slot = ci & 7;
      size_t rowb = ((size_t)(b * NSP + n0 + n)) * 256 + step * 128 + ((slot ^ (n & 7)) << 4);
      GLL((const char*)yh + rowb, (char*)ysh + (size_t)(i * 512 + (tid & ~63)) * 16);
      GLL((const char*)yl + rowb, (char*)ysl + (size_t)(i * 512 + (tid & ~63)) * 16);
    }
    __syncthreads();

#pragma unroll
    for (int kc = 0; kc < 2; ++kc) {
      const int sl = kc * 4 + hi4;
      s16x8 bfh[4], bfl[4];
#pragma unroll
      for (int fn = 0; fn < 4; ++fn) {
        int n = nbase + fn * 16 + lo16;
        int off = (int)n * 128 + ((sl ^ (n & 7)) << 4);
        bfh[fn] = *(const s16x8*)((const char*)ysh + off);
        bfl[fn] = *(const s16x8*)((const char*)ysl + off);
      }
      __builtin_amdgcn_s_setprio(1);
#pragma unroll
      for (int fo = 0; fo < 4; ++fo) {
        int o = obase + fo * 16 + lo16;
        int off = (int)o * 128 + ((sl ^ (o & 7)) << 4);
        s16x8 afh = *(const s16x8*)((const char*)wsh + off);
        s16x8 afl = *(const s16x8*)((const char*)wsl + off);
#pragma unroll
        for (int fn = 0; fn < 4; ++fn) {
          acc[fo][fn] = __builtin_amdgcn_mfma_f32_16x16x32_bf16(afh, bfh[fn], acc[fo][fn], 0, 0, 0);
          acc[fo][fn] = __builtin_amdgcn_mfma_f32_16x16x32_bf16(afh, bfl[fn], acc[fo][fn], 0, 0, 0);
          acc[fo][fn] = __builtin_amdgcn_mfma_f32_16x16x32_bf16(afl, bfh[fn], acc[fo][fn], 0, 0, 0);
        }
      }
      __builtin_amdgcn_s_setprio(0);
    }
  }

  // epilogue: bias, write wy (f32), BN partial stats
#pragma unroll
  for (int fo = 0; fo < 4; ++fo) {
    int orow = obase + fo * 16 + hi4 * 4;
    float bv[4];
#pragma unroll
    for (int r = 0; r < 4; ++r) bv[r] = bw[orow + r];
    float ss[4] = {0.f, 0.f, 0.f, 0.f}, sq[4] = {0.f, 0.f, 0.f, 0.f};
#pragma unroll
    for (int fn = 0; fn < 4; ++fn) {
      int col = n0 + nbase + fn * 16 + lo16;
#pragma unroll
      for (int r = 0; r < 4; ++r) {
        float v = acc[fo][fn][r] + bv[r];
        wy[((size_t)(b * NC) + orow + r) * NSP + col] = v;
        ss[r] += v;
        sq[r] += v * v;
      }
    }
#pragma unroll
    for (int r = 0; r < 4; ++r) {
#pragma unroll
      for (int d = 1; d < 16; d <<= 1) {
        ss[r] += __shfl_xor(ss[r], d);
        sq[r] += __shfl_xor(sq[r], d);
      }
    }
    if (lo16 == 0) {
#pragma unroll
      for (int r = 0; r < 4; ++r) {
        sums1[wc][orow + r] = ss[r];
        sums2[wc][orow + r] = sq[r];
      }
    }
  }
  __syncthreads();
  if (tid < 256) {
    atomicAdd(&s1g[tid], sums1[0][tid] + sums1[1][tid]);
    atomicAdd(&s2g[tid], sums2[0][tid] + sums2[1][tid]);
  }
}

// ---- BN (batch stats) + affine + residual, float4 ----------------------------------
__global__ __launch_bounds__(256) void bn_res4(
    const float* __restrict__ wy, const float* __restrict__ x,
    const float* __restrict__ s1, const float* __restrict__ s2,
    const float* __restrict__ gamma, const float* __restrict__ beta,
    float* __restrict__ out)
{
  int i4 = (blockIdx.x * 256 + threadIdx.x) << 2;
  int c = (i4 >> 12) & 255;
  const float cnt = 1.f / 32768.f;
  float mean = s1[c] * cnt;
  float var = s2[c] * cnt - mean * mean;
  float inv = rsqrtf(var + 1e-5f) * gamma[c];
  float bet = beta[c];
  float4 w = *(const float4*)&wy[i4];
  float4 xv = *(const float4*)&x[i4];
  float4 o;
  o.x = (w.x - mean) * inv + bet + xv.x;
  o.y = (w.y - mean) * inv + bet + xv.y;
  o.z = (w.z - mean) * inv + bet + xv.z;
  o.w = (w.w - mean) * inv + bet + xv.w;
  *(float4*)&out[i4] = o;
}

extern "C" void kernel_launch(void* const* d_in, const int* in_sizes, int n_in,
                              void* d_out, int out_size, void* d_ws, size_t ws_size,
                              hipStream_t stream) {
  const float* x    = (const float*)d_in[0];
  const float* w_g  = (const float*)d_in[1];
  const float* b_g  = (const float*)d_in[2];
  const float* w_th = (const float*)d_in[3];
  const float* b_th = (const float*)d_in[4];
  const float* w_ph = (const float*)d_in[5];
  const float* b_ph = (const float*)d_in[6];
  const float* w_w  = (const float*)d_in[7];
  const float* b_w  = (const float*)d_in[8];
  const float* gam  = (const float*)d_in[9];
  const float* bet  = (const float*)d_in[10];
  float* out = (float*)d_out;
  char* ws = (char*)d_ws;

  u16*   xh  = (u16*)(ws + OFF_XH);
  u16*   xl  = (u16*)(ws + OFF_XL);
  u16*   thT = (u16*)(ws + OFF_THT);
  u16*   phT = (u16*)(ws + OFF_PHT);
  u16*   gp  = (u16*)(ws + OFF_GP);
  u16*   yhb = (u16*)(ws + OFF_YH);
  u16*   ylb = (u16*)(ws + OFF_YL);
  float* wy  = (float*)(ws + OFF_WY);
  u16*   wbh = (u16*)(ws + OFF_WBH);
  u16*   wbl = (u16*)(ws + OFF_WBL);
  u16*   wwh = (u16*)(ws + OFF_WWH);
  u16*   wwl = (u16*)(ws + OFF_WWL);
  float* s1  = (float*)(ws + OFF_S);
  float* s2  = s1 + 256;

  wcvt<<<dim3(512), 256, 0, stream>>>(w_g, w_th, w_ph, w_w, wbh, wbl, wwh, wwl);
  zero_stats<<<dim3(1), 512, 0, stream>>>(s1);
  xt_cvt<<<dim3(64, 4, 8), 256, 0, stream>>>(x, xh, xl);

  proj_fused<<<dim3(32, 8), 512, 0, stream>>>(xh, xl, wbh, wbl, b_g, b_th, b_ph, thT, phT, gp);

  attn_mfma<<<dim3(32, 8), 256, 0, stream>>>(thT, phT, gp, yhb, ylb);

  conv_w_mfma<<<dim3(32, 8), 512, 0, stream>>>(yhb, ylb, wwh, wwl, b_w, wy, s1, s2);

  bn_res4<<<dim3(8192), 256, 0, stream>>>(wy, x, s1, s2, gam, bet, out);
}

// Round 9
// 112.025 us; speedup vs baseline: 6.2538x; 1.0674x over previous
//
#include <hip/hip_runtime.h>
#include <hip/hip_bf16.h>

// Problem constants: B=8, C=256, Ci=128, H=W=64, N=4096, M=1024
#define NB 8
#define NC 256
#define NCI 128
#define NSP 4096
#define NM 1024

typedef float f32x4 __attribute__((ext_vector_type(4)));
typedef float f32x16 __attribute__((ext_vector_type(16)));
typedef short s16x8 __attribute__((ext_vector_type(8)));
typedef unsigned short u16;

// Workspace layout (byte offsets, total < 64 MB)
#define OFF_XH  (0ull)              // xh bf16 [B][N][C]  16 MB (dead after proj)
#define OFF_XL  (16777216ull)       // xl bf16 [B][N][C]  16 MB (dead after proj)
#define OFF_THT (33554432ull)       // thT bf16 [B][N][Ci] 8 MB (dead after attn)
#define OFF_PHT (41943040ull)       // phT bf16 [B][M][Ci] 2 MB
#define OFF_GP  (44040192ull)       // gp  bf16 [B][Ci][M] 2 MB
#define OFF_YH  (46137344ull)       // yh  bf16 [B][N][Ci] 8 MB
#define OFF_YL  (54525952ull)       // yl  bf16 [B][N][Ci] 8 MB
#define OFF_WY  (0ull)              // wy f32 [B][C][N] 32 MB (overlays XH+XL, dead)
// NOTE: wy MUST be f32. BN divides by per-channel sigma(wy) which is tiny vs |mean(wy)|
// (attention output nearly constant over n) -> bf16 wy quantization (|mean|*2^-9/sigma)
// lands ~0.25 on the output. Measured twice (rounds 5, 8).
#define OFF_WBH (62914560ull)       // wb hi bf16 [384][256] 192 KB
#define OFF_WBL (63111168ull)       // wb lo
#define OFF_WWH (63307776ull)       // wwb hi bf16 [256][128] 64 KB
#define OFF_WWL (63373312ull)       // wwb lo
#define OFF_S   (63438848ull)       // s1[256], s2[256] f32

#define GLL(src, dst) __builtin_amdgcn_global_load_lds( \
    (const __attribute__((address_space(1))) unsigned*)(src), \
    (__attribute__((address_space(3))) unsigned*)(dst), 16, 0, 0)

__device__ __forceinline__ u16 f2bf(float f) {
  union { __hip_bfloat16 h; u16 u; } v;
  v.h = __float2bfloat16(f);
  return v.u;
}
__device__ __forceinline__ float bf2f(u16 u) {
  union { unsigned u; float f; } v;
  v.u = (unsigned)u << 16;
  return v.f;
}
__device__ __forceinline__ u16 bfmax4(u16 a, u16 b, u16 c, u16 d) {
  float v = fmaxf(fmaxf(bf2f(a), bf2f(b)), fmaxf(bf2f(c), bf2f(d)));
  return f2bf(v);
}
__device__ __forceinline__ unsigned cvtpk(float lo, float hi) {
  unsigned r;
  asm volatile("v_cvt_pk_bf16_f32 %0, %1, %2" : "=v"(r) : "v"(lo), "v"(hi));
  return r;
}

__global__ void zero_stats(float* s) { s[threadIdx.x] = 0.f; }

// ---- weights -> bf16 hi/lo (wb stacked: rows 0-127 g, 128-255 theta, 256-383 phi) --
__global__ __launch_bounds__(256) void wcvt(
    const float* __restrict__ wg, const float* __restrict__ wth,
    const float* __restrict__ wph, const float* __restrict__ ww,
    u16* __restrict__ wbh, u16* __restrict__ wbl,
    u16* __restrict__ wwh, u16* __restrict__ wwl)
{
  int idx = blockIdx.x * 256 + threadIdx.x;
  if (idx < 384 * 256) {
    int row = idx >> 8, k = idx & 255;
    float v = row < 128 ? wg[row * 256 + k]
            : row < 256 ? wth[(row - 128) * 256 + k]
                        : wph[(row - 256) * 256 + k];
    u16 h = f2bf(v);
    wbh[idx] = h;
    wbl[idx] = f2bf(v - bf2f(h));
  } else {
    int j = idx - 384 * 256;
    float v = ww[j];
    u16 h = f2bf(v);
    wwh[j] = h;
    wwl[j] = f2bf(v - bf2f(h));
  }
}

// ---- x [B][C][N] f32 -> xh/xl [B][N][C] bf16 hi/lo (transpose + split) -------------
__global__ __launch_bounds__(256) void xt_cvt(const float* __restrict__ x,
                                              u16* __restrict__ xh, u16* __restrict__ xl)
{
  __shared__ float t[64 * 68];
  const int n0 = blockIdx.x << 6, c0 = blockIdx.y << 6, b = blockIdx.z;
  const int tid = threadIdx.x;
  const int cl = tid >> 4, n4 = (tid & 15) << 2;
#pragma unroll
  for (int it = 0; it < 4; ++it) {
    int c = it * 16 + cl;
    float4 v = *(const float4*)&x[((size_t)(b * NC + c0 + c)) * NSP + n0 + n4];
    *(float4*)&t[c * 68 + n4] = v;
  }
  __syncthreads();
#pragma unroll
  for (int it = 0; it < 2; ++it) {
    int task = it * 256 + tid;
    int n = task >> 3, cc = (task & 7) << 3;
    u16 oh[8], ol[8];
#pragma unroll
    for (int i = 0; i < 8; ++i) {
      float v = t[(cc + i) * 68 + n];
      oh[i] = f2bf(v);
      ol[i] = f2bf(v - bf2f(oh[i]));
    }
    size_t dst = ((size_t)(b * NSP + n0 + n)) * NC + c0 + cc;
    *(s16x8*)&xh[dst] = *(s16x8*)oh;
    *(s16x8*)&xl[dst] = *(s16x8*)ol;
  }
}

// ---- fused projection: all 384 channels, 3-pass split MFMA, bias+pool+layouts ------
__global__ __launch_bounds__(512, 1) void proj_fused(
    const u16* __restrict__ xh, const u16* __restrict__ xl,
    const u16* __restrict__ wbh, const u16* __restrict__ wbl,
    const float* __restrict__ bg, const float* __restrict__ bth,
    const float* __restrict__ bph,
    u16* __restrict__ thT, u16* __restrict__ phT, u16* __restrict__ gp)
{
  __shared__ char smem[132608];
  u16* xsh = (u16*)smem;                 // [128 n][64 k]  16 KB swizzled
  u16* xsl = (u16*)(smem + 16384);       // [128 n][64 k]  16 KB
  u16* wsh = (u16*)(smem + 32768);       // [384 o][64 k]  48 KB
  u16* wsl = (u16*)(smem + 81920);       // [384 o][64 k]  48 KB
  u16* outl = (u16*)smem;                // epilogue [384][137] bf16 overlay
  float* bias = (float*)(smem + 131072); // 384 f32

  const int b = blockIdx.y, h2 = blockIdx.x;
  const int n0 = h2 << 7;
  const int tid = threadIdx.x;
  const int wave = tid >> 6, lane = tid & 63;
  const int lo16 = lane & 15, hi4 = lane >> 4;
  const int wr = wave >> 1, wc = wave & 1;
  const int obase = wr * 96, nbase = wc * 64;

  if (tid < 384)
    bias[tid] = tid < 128 ? bg[tid] : tid < 256 ? bth[tid - 128] : bph[tid - 256];

  f32x4 acc[6][4];
#pragma unroll
  for (int i = 0; i < 6; ++i)
#pragma unroll
    for (int j = 0; j < 4; ++j) acc[i][j] = (f32x4){0.f, 0.f, 0.f, 0.f};

  for (int step = 0; step < 4; ++step) {
    __syncthreads();
#pragma unroll
    for (int i = 0; i < 2; ++i) {
      int ci = i * 512 + tid;
      int n = ci >> 3, slot = ci & 7;
      size_t rowb = ((size_t)(b * NSP + n0 + n)) * 512 + step * 128 + ((slot ^ (n & 7)) << 4);
      GLL((const char*)xh + rowb, (char*)xsh + (size_t)(i * 512 + (tid & ~63)) * 16);
      GLL((const char*)xl + rowb, (char*)xsl + (size_t)(i * 512 + (tid & ~63)) * 16);
    }
#pragma unroll
    for (int i = 0; i < 6; ++i) {
      int ci = i * 512 + tid;
      int o = ci >> 3, slot = ci & 7;
      size_t rowb = (size_t)o * 512 + step * 128 + ((slot ^ (o & 7)) << 4);
      GLL((const char*)wbh + rowb, (char*)wsh + (size_t)(i * 512 + (tid & ~63)) * 16);
      GLL((const char*)wbl + rowb, (char*)wsl + (size_t)(i * 512 + (tid & ~63)) * 16);
    }
    __syncthreads();

#pragma unroll
    for (int kc = 0; kc < 2; ++kc) {
      const int sl = kc * 4 + hi4;
      s16x8 bfh[4], bfl[4];
#pragma unroll
      for (int fn = 0; fn < 4; ++fn) {
        int n = nbase + fn * 16 + lo16;
        int off = (int)n * 128 + ((sl ^ (n & 7)) << 4);
        bfh[fn] = *(const s16x8*)((const char*)xsh + off);
        bfl[fn] = *(const s16x8*)((const char*)xsl + off);
      }
      __builtin_amdgcn_s_setprio(1);
#pragma unroll
      for (int fo = 0; fo < 6; ++fo) {
        int o = obase + fo * 16 + lo16;
        int off = (int)o * 128 + ((sl ^ (o & 7)) << 4);
        s16x8 afh = *(const s16x8*)((const char*)wsh + off);
        s16x8 afl = *(const s16x8*)((const char*)wsl + off);
#pragma unroll
        for (int fn = 0; fn < 4; ++fn) {
          acc[fo][fn] = __builtin_amdgcn_mfma_f32_16x16x32_bf16(afh, bfh[fn], acc[fo][fn], 0, 0, 0);
          acc[fo][fn] = __builtin_amdgcn_mfma_f32_16x16x32_bf16(afh, bfl[fn], acc[fo][fn], 0, 0, 0);
          acc[fo][fn] = __builtin_amdgcn_mfma_f32_16x16x32_bf16(afl, bfh[fn], acc[fo][fn], 0, 0, 0);
        }
      }
      __builtin_amdgcn_s_setprio(0);
    }
  }

  __syncthreads();  // all MFMA done; staging buffers dead; outl overlays them
#pragma unroll
  for (int fo = 0; fo < 6; ++fo) {
    int orow = obase + fo * 16 + hi4 * 4;
    f32x4 bv = *(const f32x4*)&bias[orow];
#pragma unroll
    for (int fn = 0; fn < 4; ++fn) {
      int n = nbase + fn * 16 + lo16;
#pragma unroll
      for (int r = 0; r < 4; ++r)
        outl[(orow + r) * 137 + n] = f2bf(acc[fo][fn][r] + bv[r]);
    }
  }
  __syncthreads();

  // theta rows 128..255 -> thT[b][n][c]
#pragma unroll
  for (int it = 0; it < 4; ++it) {
    int task = it * 512 + tid;
    int n = task >> 4, cc = (task & 15) << 3;
    u16 o[8];
#pragma unroll
    for (int i = 0; i < 8; ++i) o[i] = outl[(128 + cc + i) * 137 + n];
    *(s16x8*)&thT[((size_t)(b * NSP + n0 + n)) * NCI + cc] = *(s16x8*)o;
  }
  // g rows 0..127, pooled -> gp[b][c][m]
  {
    int c = tid >> 2, wq = tid & 3;
    u16 o[8];
#pragma unroll
    for (int j = 0; j < 8; ++j) {
      int w2 = wq * 8 + j;
      o[j] = bfmax4(outl[c * 137 + 2 * w2], outl[c * 137 + 2 * w2 + 1],
                    outl[c * 137 + 64 + 2 * w2], outl[c * 137 + 64 + 2 * w2 + 1]);
    }
    *(s16x8*)&gp[((size_t)(b * NCI + c)) * NM + (h2 << 5) + wq * 8] = *(s16x8*)o;
  }
  // phi rows 256..383, pooled + transposed -> phT[b][m][c]
  {
    int w2 = tid >> 4, cc = (tid & 15) << 3;
    u16 o[8];
#pragma unroll
    for (int i = 0; i < 8; ++i) {
      int c = 256 + cc + i;
      o[i] = bfmax4(outl[c * 137 + 2 * w2], outl[c * 137 + 2 * w2 + 1],
                    outl[c * 137 + 64 + 2 * w2], outl[c * 137 + 64 + 2 * w2 + 1]);
    }
    *(s16x8*)&phT[((size_t)(b * NM + (h2 << 5) + w2)) * NCI + cc] = *(s16x8*)o;
  }
}

// ---- MFMA flash attention: 32x32 swapped operands + in-block split-K ----------------
// 8 waves: wave = qg (0..3) + 4*kh. Wave (qg,kh) handles 32 q, KV tiles kh*8..kh*8+7.
// End: kh=1 deposits raw (yacc,m,l) to LDS; kh=0 merges (exact online-softmax combine).
__global__ __launch_bounds__(512, 2) void attn_mfma(
    const u16* __restrict__ thT, const u16* __restrict__ phT,
    const u16* __restrict__ gP, u16* __restrict__ yh, u16* __restrict__ yl)
{
  __shared__ char smem[131072];  // dbuf[2] x half[2] x (phi 16K | g 16K)

  const int b = blockIdx.y;
  const int n0 = blockIdx.x << 7;     // 128 queries per block
  const int tid = threadIdx.x;
  const int wave = tid >> 6;
  const int qg = wave & 3;
  const int kh = wave >> 2;
  const int lane = tid & 63;
  const int l31 = lane & 31;
  const int hi1 = lane >> 5;
  const int qbase = n0 + (qg << 5);   // 32 q per wave
  const int swl = (l31 & 7) << 4;

  // theta B-fragments in registers
  s16x8 thb[8];
  {
    const u16* tr = &thT[((size_t)b * NSP + qbase + l31) * NCI + hi1 * 8];
#pragma unroll
    for (int kc = 0; kc < 8; ++kc) thb[kc] = *(const s16x8*)&tr[kc * 16];
  }

  f32x16 yacc[4];
#pragma unroll
  for (int ct = 0; ct < 4; ++ct) yacc[ct] = (f32x16)0.f;
  float m_i = -3e38f, l_i = 0.f;

  // stage tiles (step) and (step+8) into buf s: regions [h0phi][h0g][h1phi][h1g]
  auto stage = [&](int s, int step) {
    char* base = smem + s * 65536;
    const int m0a = step << 6, m0b = (step + 8) << 6;
#pragma unroll
    for (int it = 0; it < 8; ++it) {
      const int rg = it >> 1;                       // compile-time region
      int r = ((it & 1) << 9) + tid;                // chunk within region, 0..1023
      char* dst = base + rg * 16384 + (size_t)(((it & 1) << 9) + (tid & ~63)) * 16;
      if (rg == 0 || rg == 2) {
        int m0 = (rg == 0) ? m0a : m0b;
        int m = r >> 4, cb = (r & 15) << 4;
        const char* src = (const char*)phT + (((size_t)b * NM + m0 + m) << 8) + (cb ^ ((m & 7) << 4));
        GLL(src, dst);
      } else {
        int m0 = (rg == 1) ? m0a : m0b;
        int c = r >> 3, mb = (r & 7) << 4;
        const char* src = (const char*)gP + (((size_t)b * NCI + c) << 11) + m0 * 2 + (mb ^ ((c & 7) << 4));
        GLL(src, dst);
      }
    }
  };

  stage(0, 0);
  __syncthreads();
  int cur = 0;

  for (int step = 0; step < 8; ++step) {
    if (step < 7) stage(cur ^ 1, step + 1);
    const char* ph = smem + cur * 65536 + kh * 32768;
    const char* gg = ph + 16384;

    // QK^T: D[m][q], col q = l31
    f32x16 s0 = (f32x16)0.f, s1 = (f32x16)0.f;
    __builtin_amdgcn_s_setprio(1);
#pragma unroll
    for (int kc = 0; kc < 8; ++kc) {
      int cofs = (kc * 32 + hi1 * 16);
      s16x8 a0 = *(const s16x8*)(ph + l31 * 256 + (cofs ^ swl));
      s16x8 a1 = *(const s16x8*)(ph + (32 + l31) * 256 + (cofs ^ swl));
      s0 = __builtin_amdgcn_mfma_f32_32x32x16_bf16(a0, thb[kc], s0, 0, 0, 0);
      s1 = __builtin_amdgcn_mfma_f32_32x32x16_bf16(a1, thb[kc], s1, 0, 0, 0);
    }
    __builtin_amdgcn_s_setprio(0);

    // online softmax (always rescale; f32)
    float pm = s0[0];
#pragma unroll
    for (int i = 1; i < 16; ++i) pm = fmaxf(pm, s0[i]);
#pragma unroll
    for (int i = 0; i < 16; ++i) pm = fmaxf(pm, s1[i]);
    pm = fmaxf(pm, __shfl_xor(pm, 32));
    float mn = fmaxf(m_i, pm);
    float sc = __expf(m_i - mn);
    float rs = 0.f;
#pragma unroll
    for (int i = 0; i < 16; ++i) { s0[i] = __expf(s0[i] - mn); rs += s0[i]; }
#pragma unroll
    for (int i = 0; i < 16; ++i) { s1[i] = __expf(s1[i] - mn); rs += s1[i]; }
    rs += __shfl_xor(rs, 32);
    l_i = l_i * sc + rs;
    m_i = mn;
#pragma unroll
    for (int ct = 0; ct < 4; ++ct)
#pragma unroll
      for (int i = 0; i < 16; ++i) yacc[ct][i] *= sc;

    // P^T B-fragments in-register: cvt_pk + permlane32_swap
    s16x8 pb[4];
#pragma unroll
    for (int km = 0; km < 4; ++km) {
      int r0 = (km & 1) * 8;
      unsigned X0, X1, X2, X3;
      if (km < 2) {
        X0 = cvtpk(s0[r0 + 0], s0[r0 + 1]);
        X1 = cvtpk(s0[r0 + 2], s0[r0 + 3]);
        X2 = cvtpk(s0[r0 + 4], s0[r0 + 5]);
        X3 = cvtpk(s0[r0 + 6], s0[r0 + 7]);
      } else {
        X0 = cvtpk(s1[r0 + 0], s1[r0 + 1]);
        X1 = cvtpk(s1[r0 + 2], s1[r0 + 3]);
        X2 = cvtpk(s1[r0 + 4], s1[r0 + 5]);
        X3 = cvtpk(s1[r0 + 6], s1[r0 + 7]);
      }
      asm volatile("v_permlane32_swap_b32 %0, %1" : "+v"(X0), "+v"(X2));
      asm volatile("v_permlane32_swap_b32 %0, %1" : "+v"(X1), "+v"(X3));
      unsigned d[4] = {X0, X1, X2, X3};
      pb[km] = *(s16x8*)d;
    }

    // PV
    __builtin_amdgcn_s_setprio(1);
#pragma unroll
    for (int ct = 0; ct < 4; ++ct) {
      const char* grow = gg + (ct * 32 + l31) * 128;
#pragma unroll
      for (int km = 0; km < 4; ++km) {
        s16x8 ga = *(const s16x8*)(grow + ((km * 32 + hi1 * 16) ^ swl));
        yacc[ct] = __builtin_amdgcn_mfma_f32_32x32x16_bf16(ga, pb[km], yacc[ct], 0, 0, 0);
      }
    }
    __builtin_amdgcn_s_setprio(0);

    __syncthreads();
    cur ^= 1;
  }

  // ---- split-K merge ----
  float* yx = (float*)smem;               // [16 chunks][256 slots][4 f32] = 64 KB
  float* ml = (float*)(smem + 65536);     // [256 slots][2 f32]
  const int slot = (qg << 6) + lane;
  if (kh == 1) {
#pragma unroll
    for (int ct = 0; ct < 4; ++ct)
#pragma unroll
      for (int i4 = 0; i4 < 4; ++i4) {
        f32x4 v = {yacc[ct][i4 * 4 + 0], yacc[ct][i4 * 4 + 1],
                   yacc[ct][i4 * 4 + 2], yacc[ct][i4 * 4 + 3]};
        *(f32x4*)((char*)yx + (size_t)(((ct * 4 + i4) << 8) + slot) * 16) = v;
      }
    ml[slot * 2] = m_i;
    ml[slot * 2 + 1] = l_i;
  }
  __syncthreads();
  if (kh == 1) return;

  float m1 = ml[slot * 2], l1 = ml[slot * 2 + 1];
  float mm = fmaxf(m_i, m1);
  float sc0 = __expf(m_i - mm), sc1 = __expf(m1 - mm);
  float inv = 1.f / (l_i * sc0 + l1 * sc1);
  float a0 = sc0 * inv, a1 = sc1 * inv;
#pragma unroll
  for (int ct = 0; ct < 4; ++ct)
#pragma unroll
    for (int i4 = 0; i4 < 4; ++i4) {
      f32x4 v = *(const f32x4*)((const char*)yx + (size_t)(((ct * 4 + i4) << 8) + slot) * 16);
#pragma unroll
      for (int j = 0; j < 4; ++j)
        yacc[ct][i4 * 4 + j] = yacc[ct][i4 * 4 + j] * a0 + v[j] * a1;
    }

  // epilogue (waves 0-3 only, wave-private bounce -> coalesced yh/yl writes)
  u16* bounce = (u16*)(smem + 67584) + qg * 4224;   // [32 q][132]
  const int qq = lane >> 1, c0 = (lane & 1) << 6;
#pragma unroll
  for (int pass = 0; pass < 2; ++pass) {
#pragma unroll
    for (int ct = 0; ct < 4; ++ct) {
#pragma unroll
      for (int rp = 0; rp < 8; ++rp) {
        int r = rp * 2;
        int c = ct * 32 + (r & 3) + 8 * (r >> 2) + 4 * hi1;
        float v0 = yacc[ct][r], v1 = yacc[ct][r + 1];
        u16 h0 = f2bf(v0), h1 = f2bf(v1);
        u16 w0 = h0, w1 = h1;
        if (pass) { w0 = f2bf(v0 - bf2f(h0)); w1 = f2bf(v1 - bf2f(h1)); }
        *(unsigned*)&bounce[l31 * 132 + c] = (unsigned)w0 | ((unsigned)w1 << 16);
      }
    }
    asm volatile("s_waitcnt lgkmcnt(0)" ::: "memory");
    u16* dst = pass ? yl : yh;
    size_t row = ((size_t)b * NSP + qbase + qq) * NCI + c0;
#pragma unroll
    for (int k = 0; k < 8; ++k)
      *(s16x8*)&dst[row + k * 8] = *(const s16x8*)&bounce[qq * 132 + c0 + k * 8];
    asm volatile("s_waitcnt lgkmcnt(0)" ::: "memory");
  }
}

// ---- W conv 3-pass split MFMA + fused BN stats; wy f32 (mandatory, see OFF_WY) -----
__global__ __launch_bounds__(512, 1) void conv_w_mfma(
    const u16* __restrict__ yh, const u16* __restrict__ yl,
    const u16* __restrict__ wwh, const u16* __restrict__ wwl,
    const float* __restrict__ bw, float* __restrict__ wy,
    float* __restrict__ s1g, float* __restrict__ s2g)
{
  __shared__ char smem[102400];
  u16* wsh = (u16*)smem;                  // [256 o][64 k] 32 KB swizzled
  u16* wsl = (u16*)(smem + 32768);
  u16* ysh = (u16*)(smem + 65536);        // [128 n][64 k] 16 KB
  u16* ysl = (u16*)(smem + 81920);
  float (*sums1)[256] = (float(*)[256])(smem + 98304);
  float (*sums2)[256] = (float(*)[256])(smem + 100352);

  const int b = blockIdx.y, n0 = blockIdx.x << 7;
  const int tid = threadIdx.x;
  const int wave = tid >> 6, lane = tid & 63;
  const int lo16 = lane & 15, hi4 = lane >> 4;
  const int wr = wave >> 1, wc = wave & 1;
  const int obase = wr * 64, nbase = wc * 64;

  f32x4 acc[4][4];
#pragma unroll
  for (int i = 0; i < 4; ++i)
#pragma unroll
    for (int j = 0; j < 4; ++j) acc[i][j] = (f32x4){0.f, 0.f, 0.f, 0.f};

  for (int step = 0; step < 2; ++step) {
    __syncthreads();
#pragma unroll
    for (int i = 0; i < 4; ++i) {
      int ci = i * 512 + tid;
      int o = ci >> 3, slot = ci & 7;
      size_t rowb = (size_t)o * 256 + step * 128 + ((slot ^ (o & 7)) << 4);
      GLL((const char*)wwh + rowb, (char*)wsh + (size_t)(i * 512 + (tid & ~63)) * 16);
      GLL((const char*)wwl + rowb, (char*)wsl + (size_t)(i * 512 + (tid & ~63)) * 16);
    }
#pragma unroll
    for (int i = 0; i < 2; ++i) {
      int ci = i * 512 + tid;
      int n = ci >> 3, slot = ci & 7;
      size_t rowb = ((size_t)(b * NSP + n0 + n)) * 256 + step * 128 + ((slot ^ (n & 7)) << 4);
      GLL((const char*)yh + rowb, (char*)ysh + (size_t)(i * 512 + (tid & ~63)) * 16);
      GLL((const char*)yl + rowb, (char*)ysl + (size_t)(i * 512 + (tid & ~63)) * 16);
    }
    __syncthreads();

#pragma unroll
    for (int kc = 0; kc < 2; ++kc) {
      const int sl = kc * 4 + hi4;
      s16x8 bfh[4], bfl[4];
#pragma unroll
      for (int fn = 0; fn < 4; ++fn) {
        int n = nbase + fn * 16 + lo16;
        int off = (int)n * 128 + ((sl ^ (n & 7)) << 4);
        bfh[fn] = *(const s16x8*)((const char*)ysh + off);
        bfl[fn] = *(const s16x8*)((const char*)ysl + off);
      }
      __builtin_amdgcn_s_setprio(1);
#pragma unroll
      for (int fo = 0; fo < 4; ++fo) {
        int o = obase + fo * 16 + lo16;
        int off = (int)o * 128 + ((sl ^ (o & 7)) << 4);
        s16x8 afh = *(const s16x8*)((const char*)wsh + off);
        s16x8 afl = *(const s16x8*)((const char*)wsl + off);
#pragma unroll
        for (int fn = 0; fn < 4; ++fn) {
          acc[fo][fn] = __builtin_amdgcn_mfma_f32_16x16x32_bf16(afh, bfh[fn], acc[fo][fn], 0, 0, 0);
          acc[fo][fn] = __builtin_amdgcn_mfma_f32_16x16x32_bf16(afh, bfl[fn], acc[fo][fn], 0, 0, 0);
          acc[fo][fn] = __builtin_amdgcn_mfma_f32_16x16x32_bf16(afl, bfh[fn], acc[fo][fn], 0, 0, 0);
        }
      }
      __builtin_amdgcn_s_setprio(0);
    }
  }

  // epilogue: bias, write wy (f32), BN partial stats
#pragma unroll
  for (int fo = 0; fo < 4; ++fo) {
    int orow = obase + fo * 16 + hi4 * 4;
    float bv[4];
#pragma unroll
    for (int r = 0; r < 4; ++r) bv[r] = bw[orow + r];
    float ss[4] = {0.f, 0.f, 0.f, 0.f}, sq[4] = {0.f, 0.f, 0.f, 0.f};
#pragma unroll
    for (int fn = 0; fn < 4; ++fn) {
      int col = n0 + nbase + fn * 16 + lo16;
#pragma unroll
      for (int r = 0; r < 4; ++r) {
        float v = acc[fo][fn][r] + bv[r];
        wy[((size_t)(b * NC) + orow + r) * NSP + col] = v;
        ss[r] += v;
        sq[r] += v * v;
      }
    }
#pragma unroll
    for (int r = 0; r < 4; ++r) {
#pragma unroll
      for (int d = 1; d < 16; d <<= 1) {
        ss[r] += __shfl_xor(ss[r], d);
        sq[r] += __shfl_xor(sq[r], d);
      }
    }
    if (lo16 == 0) {
#pragma unroll
      for (int r = 0; r < 4; ++r) {
        sums1[wc][orow + r] = ss[r];
        sums2[wc][orow + r] = sq[r];
      }
    }
  }
  __syncthreads();
  if (tid < 256) {
    atomicAdd(&s1g[tid], sums1[0][tid] + sums1[1][tid]);
    atomicAdd(&s2g[tid], sums2[0][tid] + sums2[1][tid]);
  }
}

// ---- BN (batch stats) + affine + residual, float4 ----------------------------------
__global__ __launch_bounds__(256) void bn_res4(
    const float* __restrict__ wy, const float* __restrict__ x,
    const float* __restrict__ s1, const float* __restrict__ s2,
    const float* __restrict__ gamma, const float* __restrict__ beta,
    float* __restrict__ out)
{
  int i4 = (blockIdx.x * 256 + threadIdx.x) << 2;
  int c = (i4 >> 12) & 255;
  const float cnt = 1.f / 32768.f;
  float mean = s1[c] * cnt;
  float var = s2[c] * cnt - mean * mean;
  float inv = rsqrtf(var + 1e-5f) * gamma[c];
  float bet = beta[c];
  float4 w = *(const float4*)&wy[i4];
  float4 xv = *(const float4*)&x[i4];
  float4 o;
  o.x = (w.x - mean) * inv + bet + xv.x;
  o.y = (w.y - mean) * inv + bet + xv.y;
  o.z = (w.z - mean) * inv + bet + xv.z;
  o.w = (w.w - mean) * inv + bet + xv.w;
  *(float4*)&out[i4] = o;
}

extern "C" void kernel_launch(void* const* d_in, const int* in_sizes, int n_in,
                              void* d_out, int out_size, void* d_ws, size_t ws_size,
                              hipStream_t stream) {
  const float* x    = (const float*)d_in[0];
  const float* w_g  = (const float*)d_in[1];
  const float* b_g  = (const float*)d_in[2];
  const float* w_th = (const float*)d_in[3];
  const float* b_th = (const float*)d_in[4];
  const float* w_ph = (const float*)d_in[5];
  const float* b_ph = (const float*)d_in[6];
  const float* w_w  = (const float*)d_in[7];
  const float* b_w  = (const float*)d_in[8];
  const float* gam  = (const float*)d_in[9];
  const float* bet  = (const float*)d_in[10];
  float* out = (float*)d_out;
  char* ws = (char*)d_ws;

  u16*   xh  = (u16*)(ws + OFF_XH);
  u16*   xl  = (u16*)(ws + OFF_XL);
  u16*   thT = (u16*)(ws + OFF_THT);
  u16*   phT = (u16*)(ws + OFF_PHT);
  u16*   gp  = (u16*)(ws + OFF_GP);
  u16*   yhb = (u16*)(ws + OFF_YH);
  u16*   ylb = (u16*)(ws + OFF_YL);
  float* wy  = (float*)(ws + OFF_WY);
  u16*   wbh = (u16*)(ws + OFF_WBH);
  u16*   wbl = (u16*)(ws + OFF_WBL);
  u16*   wwh = (u16*)(ws + OFF_WWH);
  u16*   wwl = (u16*)(ws + OFF_WWL);
  float* s1  = (float*)(ws + OFF_S);
  float* s2  = s1 + 256;

  wcvt<<<dim3(512), 256, 0, stream>>>(w_g, w_th, w_ph, w_w, wbh, wbl, wwh, wwl);
  zero_stats<<<dim3(1), 512, 0, stream>>>(s1);
  xt_cvt<<<dim3(64, 4, 8), 256, 0, stream>>>(x, xh, xl);

  proj_fused<<<dim3(32, 8), 512, 0, stream>>>(xh, xl, wbh, wbl, b_g, b_th, b_ph, thT, phT, gp);

  attn_mfma<<<dim3(32, 8), 512, 0, stream>>>(thT, phT, gp, yhb, ylb);

  conv_w_mfma<<<dim3(32, 8), 512, 0, stream>>>(yhb, ylb, wwh, wwl, b_w, wy, s1, s2);

  bn_res4<<<dim3(8192), 256, 0, stream>>>(wy, x, s1, s2, gam, bet, out);
}